// Round 13
// baseline (487.077 us; speedup 1.0000x reference)
//
#include <hip/hip_runtime.h>

// Problem constants
constexpr int Bsz = 4, Ssz = 2048, Dsz = 1024, Hn = 16, dh = 64, An = 256;
constexpr size_t BSD = (size_t)Bsz * Ssz * Dsz;    // 8,388,608
constexpr size_t DD  = (size_t)Dsz * Dsz;          // 1,048,576
constexpr size_t AGD = (size_t)Bsz * Hn * An * dh; // 1,048,576
constexpr int KC = 3072;                           // concat K
constexpr size_t ACD = (size_t)Bsz * Ssz * KC;     // 25,165,824
constexpr size_t WCD = (size_t)Dsz * KC;           // 3,145,728

typedef __attribute__((ext_vector_type(8))) short bf16x8;
typedef __attribute__((ext_vector_type(4))) float f32x4;

// ---------- helpers ----------
__device__ __forceinline__ unsigned short f2bf_rn(float f) {
    unsigned int u = __float_as_uint(f);
    return (unsigned short)((u + 0x7FFFu + ((u >> 16) & 1u)) >> 16);
}
__device__ __forceinline__ float bf2f(unsigned short h) {
    return __uint_as_float(((unsigned int)h) << 16);
}
__device__ __forceinline__ void bf_split(float f, unsigned short& hi, unsigned short& lo) {
    hi = f2bf_rn(f);
    lo = f2bf_rn(f - bf2f(hi));
}
__device__ __forceinline__ void gload16(const unsigned short* g, unsigned short* l) {
    __builtin_amdgcn_global_load_lds(
        (const __attribute__((address_space(1))) unsigned int*)g,
        (__attribute__((address_space(3))) unsigned int*)l, 16, 0, 0);
}
__device__ __forceinline__ bf16x8 gfrag(const unsigned short* g) {
    return *reinterpret_cast<const bf16x8*>(g);
}
__device__ __forceinline__ void make8(float4 a, float4 b, bf16x8& hi8, bf16x8& lo8) {
    float v[8] = {a.x, a.y, a.z, a.w, b.x, b.y, b.z, b.w};
    #pragma unroll
    for (int i = 0; i < 8; ++i) {
        unsigned short h, l;
        bf_split(v[i], h, l);
        hi8[i] = (short)h; lo8[i] = (short)l;
    }
}

// Stage a row-major tile into linear LDS with source-side chunk swizzle (flash path).
template<int LOGC, int NISS>
__device__ __forceinline__ void stage_tile(const unsigned short* __restrict__ g, long rowStride,
                                           unsigned short* lbase, int t) {
    const int wid = t >> 6;
    #pragma unroll
    for (int i = 0; i < NISS; ++i) {
        int slot = i * 256 + t;
        int r = slot >> LOGC;
        int c = slot & ((1 << LOGC) - 1);
        int cs = (c ^ (r & 7)) & ((1 << LOGC) - 1);
        gload16(g + (long)r * rowStride + cs * 8, lbase + (i * 256 + wid * 64) * 8);
    }
}
template<int ROWLEN>
__device__ __forceinline__ bf16x8 fragR(const unsigned short* buf, int row, int ks, int lane) {
    int c = ks * 4 + (lane >> 4);
    int cs = (c ^ (row & 7)) & (ROWLEN / 8 - 1);
    return *reinterpret_cast<const bf16x8*>(buf + row * ROWLEN + cs * 8);
}

// ---------- split kernels (concat layout, R11-validated) ----------
// inputs -> concat A' [8192][3072] = [hi | hi | lo]
__global__ __launch_bounds__(256)
void split_inputs(const float* __restrict__ q, const float* __restrict__ k,
                  const float* __restrict__ v,
                  unsigned short* __restrict__ Aq, unsigned short* __restrict__ Ak,
                  unsigned short* __restrict__ Av)
{
    const int job = blockIdx.y;
    const float* src = (job == 0) ? q : (job == 1) ? k : v;
    unsigned short* dst = (job == 0) ? Aq : (job == 1) ? Ak : Av;
    int idx4 = blockIdx.x * 256 + threadIdx.x;
    int row = idx4 >> 8;
    int col = (idx4 & 255) * 4;
    float4 v4 = reinterpret_cast<const float4*>(src)[idx4];
    ushort4 h, l;
    bf_split(v4.x, h.x, l.x);
    bf_split(v4.y, h.y, l.y);
    bf_split(v4.z, h.z, l.z);
    bf_split(v4.w, h.w, l.w);
    unsigned short* rp = dst + (size_t)row * KC + col;
    *reinterpret_cast<ushort4*>(rp)        = h;
    *reinterpret_cast<ushort4*>(rp + 1024) = h;
    *reinterpret_cast<ushort4*>(rp + 2048) = l;
}

// weights: jobs 0-2 -> concat W' [1024][3072] = [hi | lo | hi]; job 3 -> wo_hi/wo_lo
__global__ __launch_bounds__(256)
void split_weights(const float* __restrict__ Wq, const float* __restrict__ Wk,
                   const float* __restrict__ Wv, const float* __restrict__ Wo,
                   unsigned short* __restrict__ Wc,
                   unsigned short* __restrict__ wo_hi, unsigned short* __restrict__ wo_lo)
{
    const int job = blockIdx.y;
    const float* src = (job == 0) ? Wq : (job == 1) ? Wk : (job == 2) ? Wv : Wo;
    int idx4 = blockIdx.x * 256 + threadIdx.x;
    float4 v4 = reinterpret_cast<const float4*>(src)[idx4];
    ushort4 h, l;
    bf_split(v4.x, h.x, l.x);
    bf_split(v4.y, h.y, l.y);
    bf_split(v4.z, h.z, l.z);
    bf_split(v4.w, h.w, l.w);
    if (job < 3) {
        int row = idx4 >> 8;
        int col = (idx4 & 255) * 4;
        unsigned short* rp = Wc + (size_t)job * WCD + (size_t)row * KC + col;
        *reinterpret_cast<ushort4*>(rp)        = h;
        *reinterpret_cast<ushort4*>(rp + 1024) = l;
        *reinterpret_cast<ushort4*>(rp + 2048) = h;
    } else {
        reinterpret_cast<ushort4*>(wo_hi)[idx4] = h;
        reinterpret_cast<ushort4*>(wo_lo)[idx4] = l;
    }
}

// ---------- 8-phase-style pipelined GEMM for QKV ----------
// 256x256 tile, BK=32, 512 threads (8 waves = 2M x 4N), 4-deep LDS ring (128 KB).
// Per K-tile: 2 phases x {ds_read regs; stage half of tile kt+2; barrier; MFMA x16; barrier}.
// vmcnt(4) once per tile boundary (counted, never 0 until drain).
__global__ __launch_bounds__(512, 2)
void gemm_qkv_8ph(const unsigned short* __restrict__ Aq, const unsigned short* __restrict__ Ak,
                  const unsigned short* __restrict__ Av, const unsigned short* __restrict__ Wc,
                  const float* __restrict__ bq, const float* __restrict__ bk, const float* __restrict__ bv,
                  unsigned short* __restrict__ qh_hi, unsigned short* __restrict__ qh_lo,
                  unsigned short* __restrict__ kh_hi, unsigned short* __restrict__ kh_lo,
                  unsigned short* __restrict__ vt_hi, unsigned short* __restrict__ vt_lo,
                  unsigned short* __restrict__ ag_hi, unsigned short* __restrict__ ag_lo)
{
    __shared__ unsigned short lds4[4 * 16384];   // 4 ring buffers x (A 16KB + B 16KB)

    const int t = threadIdx.x, lane = t & 63, wid = t >> 6;
    const int al15 = lane & 15, g4 = lane >> 4;
    const int wr = wid >> 2, wc = wid & 3;       // wave grid 2M x 4N

    const int id = blockIdx.x;
    const int z = id >> 7, rem = id & 127;
    const int xcd = rem & 7, slot = rem >> 3;    // xcd-swizzled panels
    const int m0 = (xcd * 4 + (slot >> 2)) * 256;
    const int n0 = (slot & 3) * 256;

    const unsigned short* A = (z == 0) ? Aq : (z == 1) ? Ak : Av;
    const unsigned short* B = Wc + (size_t)z * WCD;
    const float* bias = (z == 0) ? bq : (z == 1) ? bk : bv;
    unsigned short* Chi = (z == 0) ? qh_hi : (z == 1) ? kh_hi : vt_hi;
    unsigned short* Clo = (z == 0) ? qh_lo : (z == 1) ? kh_lo : vt_lo;

    // per-thread staging offsets (tile-independent): slot = i*512 + t; r = slot>>2; cp = slot&3;
    // source chunk c = cp ^ ((r>>1)&3)  (inverse-swizzled source -> linear LDS dest)
    size_t asrc[2], bsrc[2];
    int dsto[2];
    #pragma unroll
    for (int i = 0; i < 2; ++i) {
        int sl = i * 512 + t;
        int r = sl >> 2, cp = sl & 3;
        int c = cp ^ ((r >> 1) & 3);
        asrc[i] = (size_t)(m0 + r) * KC + c * 8;
        bsrc[i] = (size_t)(n0 + r) * KC + c * 8;
        dsto[i] = (i * 512 + wid * 64) * 8;
    }

    f32x4 acc[8][4];
    #pragma unroll
    for (int i = 0; i < 8; ++i)
        #pragma unroll
        for (int j = 0; j < 4; ++j)
            acc[i][j] = f32x4{0.f, 0.f, 0.f, 0.f};

    constexpr int NT = KC / 32;   // 96 K-tiles

    // prologue: stage tiles 0 and 1; confirm tile 0 resident
    #pragma unroll
    for (int kt0 = 0; kt0 < 2; ++kt0) {
        unsigned short* buf = lds4 + kt0 * 16384;
        #pragma unroll
        for (int i = 0; i < 2; ++i)
            gload16(A + asrc[i] + kt0 * 32, buf + dsto[i]);
        #pragma unroll
        for (int i = 0; i < 2; ++i)
            gload16(B + bsrc[i] + kt0 * 32, buf + 8192 + dsto[i]);
    }
    asm volatile("s_waitcnt vmcnt(4)" ::: "memory");
    __builtin_amdgcn_s_barrier();

    bf16x8 bf[4];

    #pragma unroll 1
    for (int kt = 0; kt < NT; ++kt) {
        const unsigned short* bufA = lds4 + (kt & 3) * 16384;
        const unsigned short* bufB = bufA + 8192;
        unsigned short* sbuf = lds4 + ((kt + 2) & 3) * 16384;
        const bool st = (kt + 2) < NT;

        // ---- phase 1: B regs (4) + A quad 0 (4); stage A-half of kt+2 ----
        bf16x8 af[4];
        #pragma unroll
        for (int nf = 0; nf < 4; ++nf) {
            int row = wc * 64 + nf * 16 + al15;
            int c = g4 ^ ((row >> 1) & 3);
            bf[nf] = *reinterpret_cast<const bf16x8*>(bufB + row * 32 + c * 8);
        }
        #pragma unroll
        for (int mf = 0; mf < 4; ++mf) {
            int row = wr * 128 + mf * 16 + al15;
            int c = g4 ^ ((row >> 1) & 3);
            af[mf] = *reinterpret_cast<const bf16x8*>(bufA + row * 32 + c * 8);
        }
        if (st) {
            #pragma unroll
            for (int i = 0; i < 2; ++i)
                gload16(A + asrc[i] + (size_t)(kt + 2) * 32, sbuf + dsto[i]);
        }
        __builtin_amdgcn_s_barrier();
        asm volatile("s_waitcnt lgkmcnt(0)" ::: "memory");
        __builtin_amdgcn_s_setprio(1);
        #pragma unroll
        for (int mf = 0; mf < 4; ++mf)
            #pragma unroll
            for (int nf = 0; nf < 4; ++nf)
                acc[mf][nf] = __builtin_amdgcn_mfma_f32_16x16x32_bf16(af[mf], bf[nf], acc[mf][nf], 0, 0, 0);
        __builtin_amdgcn_s_setprio(0);
        __builtin_amdgcn_s_barrier();

        // ---- phase 2: A quad 1 (4); stage B-half of kt+2; tile-boundary vmcnt ----
        #pragma unroll
        for (int mf = 0; mf < 4; ++mf) {
            int row = wr * 128 + (4 + mf) * 16 + al15;
            int c = g4 ^ ((row >> 1) & 3);
            af[mf] = *reinterpret_cast<const bf16x8*>(bufA + row * 32 + c * 8);
        }
        if (st) {
            #pragma unroll
            for (int i = 0; i < 2; ++i)
                gload16(B + bsrc[i] + (size_t)(kt + 2) * 32, sbuf + 8192 + dsto[i]);
        }
        if (kt == NT - 2)
            asm volatile("s_waitcnt vmcnt(0)" ::: "memory");
        else if (kt < NT - 2)
            asm volatile("s_waitcnt vmcnt(4)" ::: "memory");
        __builtin_amdgcn_s_barrier();
        asm volatile("s_waitcnt lgkmcnt(0)" ::: "memory");
        __builtin_amdgcn_s_setprio(1);
        #pragma unroll
        for (int mf = 0; mf < 4; ++mf)
            #pragma unroll
            for (int nf = 0; nf < 4; ++nf)
                acc[4 + mf][nf] = __builtin_amdgcn_mfma_f32_16x16x32_bf16(af[mf], bf[nf], acc[4 + mf][nf], 0, 0, 0);
        __builtin_amdgcn_s_setprio(0);
        __builtin_amdgcn_s_barrier();
    }

    // ---- epilogue: z-dependent layouts + fused agent pooling (z==0) ----
    #pragma unroll
    for (int mf = 0; mf < 8; ++mf) {
        #pragma unroll
        for (int nf = 0; nf < 4; ++nf) {
            const int n = n0 + wc * 64 + nf * 16 + al15;
            const float bval = bias[n];
            float psum = 0.f;
            #pragma unroll
            for (int j = 0; j < 4; ++j) {
                const int m = m0 + wr * 128 + mf * 16 + (g4 << 2) + j;
                float val = acc[mf][nf][j] + bval;
                psum += val;
                const int b = m >> 11, s = m & (Ssz - 1);
                const int h = n >> 6, c = n & (dh - 1);
                size_t idx;
                if (z == 0)
                    idx = (size_t)(b * Hn + h) * 131072
                        + (((s >> 4) * 2 + (c >> 5)) << 9)
                        + (((c >> 3) & 3) << 7) + ((s & 15) << 3) + (c & 7);
                else if (z == 1)
                    idx = (((size_t)(b * Hn + h)) * Ssz + s) * dh + c;
                else
                    idx = (((size_t)(b * Hn + h)) * dh + c) * Ssz + s;
                unsigned short hi, lo;
                bf_split(val, hi, lo);
                Chi[idx] = hi; Clo[idx] = lo;
            }
            if (z == 0) {
                psum += __shfl_xor(psum, 16);
                if (((lane >> 4) & 1) == 0) {
                    const float agv = psum * 0.125f;
                    const int mrow = m0 + wr * 128 + mf * 16;
                    const int b = mrow >> 11, sRow = mrow & (Ssz - 1);
                    const int h = n >> 6, c = n & (dh - 1);
                    const int a = (sRow >> 3) + ((lane >> 5) & 1);
                    const int bh_ = b * Hn + h;
                    unsigned short hi, lo;
                    bf_split(agv, hi, lo);
                    const size_t oidx = (size_t)bh_ * 16384
                        + (((a >> 4) * 2 + (c >> 5)) << 9) + (((c >> 3) & 3) << 7)
                        + ((a & 15) << 3) + (c & 7);
                    ag_hi[oidx] = hi; ag_lo[oidx] = lo;
                }
            }
        }
    }
}

// ---------- old-structure GEMM (output projection only) ----------
#define MT 128
#define BKm 32

__device__ __forceinline__ bf16x8 lds_frag(const unsigned short* buf, int baseRow, int lane) {
    int row = baseRow + (lane & 15);
    int c = lane >> 4;
    int idx = row * 32 + ((c ^ ((row >> 1) & 3)) << 3);
    return *reinterpret_cast<const bf16x8*>(buf + idx);
}

__global__ __launch_bounds__(256, 2)
void gemm_out(const unsigned short* __restrict__ Ahi_, const unsigned short* __restrict__ Alo_,
              const unsigned short* __restrict__ Bhi_, const unsigned short* __restrict__ Blo_,
              const float* __restrict__ bias, float* __restrict__ Cf)
{
    const int rem = blockIdx.x & 511;
    const int xcd = rem & 7, slot = rem >> 3;
    const int m0 = (xcd * 8 + (slot >> 3)) * MT;
    const int n0 = (slot & 7) * MT;

    __shared__ unsigned short lds[4 * 4096];
    const int t = threadIdx.x;
    const int lane = t & 63, wid = t >> 6;
    const int wr = wid >> 1, wc = wid & 1;
    const int srow0 = t >> 2;
    const int x4 = t & 3;
    const int ldsBase0 = (wid * 64) * 8;
    const int ldsBase1 = (256 + wid * 64) * 8;
    f32x4 acc[4][4];
    #pragma unroll
    for (int i = 0; i < 4; ++i)
        #pragma unroll
        for (int j = 0; j < 4; ++j)
            acc[i][j] = f32x4{0.f, 0.f, 0.f, 0.f};
    const unsigned short* gA[2] = {Ahi_, Alo_};
    const unsigned short* gB[2] = {Bhi_, Blo_};
    for (int k0 = 0; k0 < Dsz; k0 += BKm) {
        #pragma unroll
        for (int hb = 0; hb < 2; ++hb) {
            {
                const unsigned short* G = gA[hb];
                int r0 = srow0, r1 = srow0 + 64;
                int c0 = x4 ^ ((r0 >> 1) & 3);
                int c1 = x4 ^ ((r1 >> 1) & 3);
                gload16(G + (size_t)(m0 + r0) * Dsz + k0 + c0 * 8, lds + hb * 4096 + ldsBase0);
                gload16(G + (size_t)(m0 + r1) * Dsz + k0 + c1 * 8, lds + hb * 4096 + ldsBase1);
            }
            {
                const unsigned short* G = gB[hb];
                int r0 = srow0, r1 = srow0 + 64;
                int c0 = x4 ^ ((r0 >> 1) & 3);
                int c1 = x4 ^ ((r1 >> 1) & 3);
                gload16(G + (size_t)(n0 + r0) * Dsz + k0 + c0 * 8, lds + (2 + hb) * 4096 + ldsBase0);
                gload16(G + (size_t)(n0 + r1) * Dsz + k0 + c1 * 8, lds + (2 + hb) * 4096 + ldsBase1);
            }
        }
        __syncthreads();
        bf16x8 ah[4], al[4], bh[4], bl[4];
        #pragma unroll
        for (int mi = 0; mi < 4; ++mi) {
            ah[mi] = lds_frag(lds + 0 * 4096, wr * 64 + mi * 16, lane);
            al[mi] = lds_frag(lds + 1 * 4096, wr * 64 + mi * 16, lane);
        }
        #pragma unroll
        for (int ni = 0; ni < 4; ++ni) {
            bh[ni] = lds_frag(lds + 2 * 4096, wc * 64 + ni * 16, lane);
            bl[ni] = lds_frag(lds + 3 * 4096, wc * 64 + ni * 16, lane);
        }
        #pragma unroll
        for (int mi = 0; mi < 4; ++mi)
            #pragma unroll
            for (int ni = 0; ni < 4; ++ni) {
                acc[mi][ni] = __builtin_amdgcn_mfma_f32_16x16x32_bf16(ah[mi], bh[ni], acc[mi][ni], 0, 0, 0);
                acc[mi][ni] = __builtin_amdgcn_mfma_f32_16x16x32_bf16(ah[mi], bl[ni], acc[mi][ni], 0, 0, 0);
                acc[mi][ni] = __builtin_amdgcn_mfma_f32_16x16x32_bf16(al[mi], bh[ni], acc[mi][ni], 0, 0, 0);
            }
        __syncthreads();
    }

    #pragma unroll
    for (int mi = 0; mi < 4; ++mi) {
        #pragma unroll
        for (int ni = 0; ni < 4; ++ni) {
            const int n = n0 + wc * 64 + ni * 16 + (lane & 15);
            const float bval = bias[n];
            #pragma unroll
            for (int j = 0; j < 4; ++j) {
                const int m = m0 + wr * 64 + mi * 16 + ((lane >> 4) << 2) + j;
                Cf[(size_t)m * Dsz + n] = acc[mi][ni][j] + bval;
            }
        }
    }
}

// ---------- flash stage-1: XCD-co-located flat grid (id&63 = bh) ----------
__global__ __launch_bounds__(256, 3)
void flash1(const unsigned short* __restrict__ ag_hi, const unsigned short* __restrict__ ag_lo,
            const unsigned short* __restrict__ kh_hi, const unsigned short* __restrict__ kh_lo,
            const unsigned short* __restrict__ vt_hi_g, const unsigned short* __restrict__ vt_lo_g,
            unsigned short* __restrict__ avt_hi, unsigned short* __restrict__ avt_lo)
{
    __shared__ unsigned short lds[24576];
    unsigned short* kth = lds;
    unsigned short* ktl = lds + 4096;
    unsigned short* vth = lds + 8192;
    unsigned short* vtl = lds + 12288;
    const int t = threadIdx.x;
    const int lane = t & 63, w = t >> 6;
    const int al15 = lane & 15, hi4 = lane >> 4;
    unsigned short* pwh = lds + 16384 + w * 2048;
    unsigned short* pwl = pwh + 1024;

    const int bh = blockIdx.x & 63;
    const int a0 = (blockIdx.x >> 6) * 64;

    bf16x8 bqh[2], bql[2];
    {
        const size_t abase = (size_t)bh * 16384 + (size_t)((a0 >> 4) + w) * 1024;
        #pragma unroll
        for (int ks = 0; ks < 2; ++ks) {
            bqh[ks] = gfrag(ag_hi + abase + ks * 512 + lane * 8);
            bql[ks] = gfrag(ag_lo + abase + ks * 512 + lane * 8);
        }
    }

    f32x4 O[4];
    #pragma unroll
    for (int i = 0; i < 4; ++i) O[i] = f32x4{0.f, 0.f, 0.f, 0.f};
    float m_run = -INFINITY, l_run = 0.f;

    for (int s0 = 0; s0 < Ssz; s0 += 64) {
        stage_tile<3, 2>(kh_hi + ((size_t)bh * Ssz + s0) * dh, dh, kth, t);
        stage_tile<3, 2>(kh_lo + ((size_t)bh * Ssz + s0) * dh, dh, ktl, t);
        stage_tile<3, 2>(vt_hi_g + (size_t)bh * dh * Ssz + s0, Ssz, vth, t);
        stage_tile<3, 2>(vt_lo_g + (size_t)bh * dh * Ssz + s0, Ssz, vtl, t);
        __syncthreads();

        f32x4 sc[4];
        #pragma unroll
        for (int si = 0; si < 4; ++si) sc[si] = f32x4{0.f, 0.f, 0.f, 0.f};
        #pragma unroll
        for (int si = 0; si < 4; ++si)
            #pragma unroll
            for (int ks = 0; ks < 2; ++ks) {
                bf16x8 ah = fragR<64>(kth, si * 16 + al15, ks, lane);
                bf16x8 al = fragR<64>(ktl, si * 16 + al15, ks, lane);
                sc[si] = __builtin_amdgcn_mfma_f32_16x16x32_bf16(ah, bqh[ks], sc[si], 0, 0, 0);
                sc[si] = __builtin_amdgcn_mfma_f32_16x16x32_bf16(ah, bql[ks], sc[si], 0, 0, 0);
                sc[si] = __builtin_amdgcn_mfma_f32_16x16x32_bf16(al, bqh[ks], sc[si], 0, 0, 0);
            }

        float tmax = -INFINITY;
        #pragma unroll
        for (int si = 0; si < 4; ++si)
            #pragma unroll
            for (int j = 0; j < 4; ++j) {
                sc[si][j] *= 0.125f;
                tmax = fmaxf(tmax, sc[si][j]);
            }
        tmax = fmaxf(tmax, __shfl_xor(tmax, 16));
        tmax = fmaxf(tmax, __shfl_xor(tmax, 32));
        float newm = fmaxf(m_run, tmax);
        float fac = __expf(m_run - newm);
        float tsum = 0.f;
        #pragma unroll
        for (int si = 0; si < 4; ++si)
            #pragma unroll
            for (int j = 0; j < 4; ++j) {
                float p = __expf(sc[si][j] - newm);
                sc[si][j] = p;
                tsum += p;
            }
        tsum += __shfl_xor(tsum, 16);
        tsum += __shfl_xor(tsum, 32);
        l_run = l_run * fac + tsum;
        m_run = newm;

        #pragma unroll
        for (int si = 0; si < 4; ++si) {
            ushort4 h4, l4;
            bf_split(sc[si][0], h4.x, l4.x);
            bf_split(sc[si][1], h4.y, l4.y);
            bf_split(sc[si][2], h4.z, l4.z);
            bf_split(sc[si][3], h4.w, l4.w);
            int baseS = si * 16 + (hi4 << 2);
            int addr = al15 * 64 + (baseS ^ ((al15 & 7) << 3));
            *reinterpret_cast<ushort4*>(pwh + addr) = h4;
            *reinterpret_cast<ushort4*>(pwl + addr) = l4;
        }

        float fj[4];
        #pragma unroll
        for (int j = 0; j < 4; ++j) fj[j] = __shfl(fac, (hi4 << 2) + j);
        #pragma unroll
        for (int di = 0; di < 4; ++di)
            #pragma unroll
            for (int j = 0; j < 4; ++j) O[di][j] *= fj[j];

        #pragma unroll
        for (int ks = 0; ks < 2; ++ks) {
            bf16x8 pah = fragR<64>(pwh, al15, ks, lane);
            bf16x8 pal = fragR<64>(pwl, al15, ks, lane);
            #pragma unroll
            for (int di = 0; di < 4; ++di) {
                bf16x8 vh = fragR<64>(vth, di * 16 + al15, ks, lane);
                bf16x8 vl = fragR<64>(vtl, di * 16 + al15, ks, lane);
                O[di] = __builtin_amdgcn_mfma_f32_16x16x32_bf16(pah, vh, O[di], 0, 0, 0);
                O[di] = __builtin_amdgcn_mfma_f32_16x16x32_bf16(pah, vl, O[di], 0, 0, 0);
                O[di] = __builtin_amdgcn_mfma_f32_16x16x32_bf16(pal, vh, O[di], 0, 0, 0);
            }
        }
        __syncthreads();
    }

    float lj[4];
    #pragma unroll
    for (int j = 0; j < 4; ++j) lj[j] = __shfl(l_run, (hi4 << 2) + j);
    #pragma unroll
    for (int di = 0; di < 4; ++di) {
        ushort4 h4, l4;
        #pragma unroll
        for (int j = 0; j < 4; ++j) {
            float val = O[di][j] / lj[j];
            unsigned short hi, lo;
            bf_split(val, hi, lo);
            ((unsigned short*)&h4)[j] = hi;
            ((unsigned short*)&l4)[j] = lo;
        }
        const size_t oidx = (size_t)bh * 16384
            + (size_t)(di * 8 + (a0 >> 5) + (w >> 1)) * 512
            + (size_t)((2 * w + (hi4 >> 1)) & 3) * 128
            + al15 * 8 + (hi4 & 1) * 4;
        *reinterpret_cast<ushort4*>(avt_hi + oidx) = h4;
        *reinterpret_cast<ushort4*>(avt_lo + oidx) = l4;
    }
}

// ---------- flash stage-2: XCD-co-located flat grid (id&63 = bh) ----------
__global__ __launch_bounds__(256, 2)
void flash2(const unsigned short* __restrict__ qh_hi, const unsigned short* __restrict__ qh_lo,
            const unsigned short* __restrict__ ag_hi, const unsigned short* __restrict__ ag_lo,
            const unsigned short* __restrict__ avt_hi, const unsigned short* __restrict__ avt_lo,
            float* __restrict__ q_attn,
            unsigned short* __restrict__ xo_hi, unsigned short* __restrict__ xo_lo)
{
    __shared__ float plds[4][4096];

    const int t = threadIdx.x, lane = t & 63, w = t >> 6;
    const int al15 = lane & 15, hi4 = lane >> 4;
    const int bh = blockIdx.x & 63;
    const int s0 = (blockIdx.x >> 6) * 64;
    float* P = plds[w];

    bf16x8 bqh[2], bql[2];
    {
        const size_t qbase = (size_t)bh * 131072 + (size_t)((s0 >> 4) + w) * 1024;
        #pragma unroll
        for (int ks = 0; ks < 2; ++ks) {
            bqh[ks] = gfrag(qh_hi + qbase + ks * 512 + lane * 8);
            bql[ks] = gfrag(qh_lo + qbase + ks * 512 + lane * 8);
        }
    }

    const unsigned short* agh = ag_hi + (size_t)bh * 16384;
    const unsigned short* agl = ag_lo + (size_t)bh * 16384;
    f32x4 acc[16];
    #pragma unroll
    for (int ai = 0; ai < 16; ++ai) acc[ai] = f32x4{0.f, 0.f, 0.f, 0.f};
    #pragma unroll
    for (int ai = 0; ai < 16; ++ai)
        #pragma unroll
        for (int ks = 0; ks < 2; ++ks) {
            bf16x8 ah = gfrag(agh + (ai * 2 + ks) * 512 + lane * 8);
            bf16x8 al = gfrag(agl + (ai * 2 + ks) * 512 + lane * 8);
            acc[ai] = __builtin_amdgcn_mfma_f32_16x16x32_bf16(ah, bqh[ks], acc[ai], 0, 0, 0);
            acc[ai] = __builtin_amdgcn_mfma_f32_16x16x32_bf16(ah, bql[ks], acc[ai], 0, 0, 0);
            acc[ai] = __builtin_amdgcn_mfma_f32_16x16x32_bf16(al, bqh[ks], acc[ai], 0, 0, 0);
        }

    float mx = -INFINITY;
    #pragma unroll
    for (int ai = 0; ai < 16; ++ai)
        #pragma unroll
        for (int j = 0; j < 4; ++j) {
            acc[ai][j] *= 0.125f;
            mx = fmaxf(mx, acc[ai][j]);
        }
    mx = fmaxf(mx, __shfl_xor(mx, 16));
    mx = fmaxf(mx, __shfl_xor(mx, 32));
    float sum = 0.f;
    #pragma unroll
    for (int ai = 0; ai < 16; ++ai)
        #pragma unroll
        for (int j = 0; j < 4; ++j) {
            float p = __expf(acc[ai][j] - mx);
            acc[ai][j] = p;
            sum += p;
        }
    sum += __shfl_xor(sum, 16);
    sum += __shfl_xor(sum, 32);
    const float inv = 1.0f / sum;

    #pragma unroll
    for (int ai = 0; ai < 16; ++ai) {
        float4 o;
        o.x = acc[ai][0] * inv; o.y = acc[ai][1] * inv;
        o.z = acc[ai][2] * inv; o.w = acc[ai][3] * inv;
        int pos4 = (ai * 4 + hi4) ^ (al15 & 7);
        *reinterpret_cast<float4*>(P + al15 * 256 + pos4 * 4) = o;
    }

    {
        float* qbase = q_attn + ((size_t)bh * Ssz + s0 + w * 16) * An;
        #pragma unroll
        for (int r = 0; r < 16; ++r) {
            float4 f = *reinterpret_cast<const float4*>(P + r * 256 + ((lane ^ (r & 7)) * 4));
            *reinterpret_cast<float4*>(qbase + r * An + lane * 4) = f;
        }
    }

    const unsigned short* avh_b = avt_hi + (size_t)bh * 16384;
    const unsigned short* avl_b = avt_lo + (size_t)bh * 16384;
    f32x4 O[4];
    #pragma unroll
    for (int i = 0; i < 4; ++i) O[i] = f32x4{0.f, 0.f, 0.f, 0.f};
    #pragma unroll
    for (int ks = 0; ks < 8; ++ks) {
        int p4 = ks * 8 + hi4 * 2;
        float4 fa = *reinterpret_cast<const float4*>(P + al15 * 256 + ((p4 ^ (al15 & 7)) * 4));
        float4 fb = *reinterpret_cast<const float4*>(P + al15 * 256 + (((p4 + 1) ^ (al15 & 7)) * 4));
        bf16x8 pah, pal;
        make8(fa, fb, pah, pal);
        #pragma unroll
        for (int di = 0; di < 4; ++di) {
            bf16x8 avh = gfrag(avh_b + (di * 8 + ks) * 512 + lane * 8);
            bf16x8 avl = gfrag(avl_b + (di * 8 + ks) * 512 + lane * 8);
            O[di] = __builtin_amdgcn_mfma_f32_16x16x32_bf16(pah, avh, O[di], 0, 0, 0);
            O[di] = __builtin_amdgcn_mfma_f32_16x16x32_bf16(pah, avl, O[di], 0, 0, 0);
            O[di] = __builtin_amdgcn_mfma_f32_16x16x32_bf16(pal, avh, O[di], 0, 0, 0);
        }
    }

    const int b = bh >> 4, h = bh & (Hn - 1);
    #pragma unroll
    for (int di = 0; di < 4; ++di)
        #pragma unroll
        for (int j = 0; j < 4; ++j) {
            float val = O[di][j];
            int sG = s0 + w * 16 + (hi4 << 2) + j;
            int dfull = h * dh + di * 16 + al15;
            size_t idx = ((size_t)b * Ssz + sG) * Dsz + dfull;
            unsigned short hi, lo;
            bf_split(val, hi, lo);
            xo_hi[idx] = hi; xo_lo[idx] = lo;
        }
}

extern "C" void kernel_launch(void* const* d_in, const int* in_sizes, int n_in,
                              void* d_out, int out_size, void* d_ws, size_t ws_size,
                              hipStream_t stream)
{
    const float* q  = (const float*)d_in[0];
    const float* k  = (const float*)d_in[1];
    const float* v  = (const float*)d_in[2];
    const float* Wq = (const float*)d_in[3];
    const float* bq = (const float*)d_in[4];
    const float* Wk = (const float*)d_in[5];
    const float* bk = (const float*)d_in[6];
    const float* Wv = (const float*)d_in[7];
    const float* bv = (const float*)d_in[8];
    const float* Wo = (const float*)d_in[9];
    const float* bo = (const float*)d_in[10];

    float* out    = (float*)d_out;
    float* q_attn = out + BSD;

    unsigned short* u = (unsigned short*)d_ws;
    unsigned short* Aq    = u;                  // concat A' [8192][3072]
    unsigned short* Ak    = Aq + ACD;
    unsigned short* Av    = Ak + ACD;
    unsigned short* Wc    = Av + ACD;           // concat W' [3][1024][3072]
    unsigned short* wo_hi = Wc + 3 * WCD;       // Wo split
    unsigned short* wo_lo = wo_hi + DD;
    unsigned short* qh_hi = wo_lo + DD;         // qh TILE layout
    unsigned short* qh_lo = qh_hi + BSD;
    unsigned short* kh_hi = qh_lo + BSD;        // [B,H,S,dh]
    unsigned short* kh_lo = kh_hi + BSD;
    unsigned short* vt_hi = kh_lo + BSD;        // [B,H,dh,S]
    unsigned short* vt_lo = vt_hi + BSD;
    unsigned short* xo_hi = vt_lo + BSD;        // out_h split [B,S,D]
    unsigned short* xo_lo = xo_hi + BSD;
    unsigned short* ag_hi = xo_lo + BSD;        // agents TILE
    unsigned short* ag_lo = ag_hi + AGD;
    unsigned short* avt_hi = ag_lo + AGD;       // avt TILE
    unsigned short* avt_lo = avt_hi + AGD;

    // 1) splits (concat layout)
    split_inputs<<<dim3(BSD / 1024, 3), 256, 0, stream>>>(q, k, v, Aq, Ak, Av);
    split_weights<<<dim3(DD / 1024, 4), 256, 0, stream>>>(Wq, Wk, Wv, Wo, Wc, wo_hi, wo_lo);

    // 2) QKV projections — 8-phase-style pipelined 256² GEMM + fused agent pooling
    gemm_qkv_8ph<<<384, 512, 0, stream>>>(
        Aq, Ak, Av, Wc, bq, bk, bv,
        qh_hi, qh_lo, kh_hi, kh_lo, vt_hi, vt_lo, ag_hi, ag_lo);

    // 3) stage 1 flash
    flash1<<<256, 256, 0, stream>>>(
        ag_hi, ag_lo, kh_hi, kh_lo, vt_hi, vt_lo, avt_hi, avt_lo);

    // 4) stage 2 flash -> q_attn + out_h
    flash2<<<2048, 256, 0, stream>>>(
        qh_hi, qh_lo, ag_hi, ag_lo, avt_hi, avt_lo, q_attn, xo_hi, xo_lo);

    // 5) output projection
    gemm_out<<<512, 256, 0, stream>>>(
        xo_hi, xo_lo, wo_hi, wo_lo, bo, out);
}

// Round 14
// 448.736 us; speedup vs baseline: 1.0854x; 1.0854x over previous
//
#include <hip/hip_runtime.h>

// Problem constants
constexpr int Bsz = 4, Ssz = 2048, Dsz = 1024, Hn = 16, dh = 64, An = 256;
constexpr size_t BSD = (size_t)Bsz * Ssz * Dsz;    // 8,388,608
constexpr size_t DD  = (size_t)Dsz * Dsz;          // 1,048,576
constexpr size_t AGD = (size_t)Bsz * Hn * An * dh; // 1,048,576
constexpr int KC = 3072;                           // concat K
constexpr size_t ACD = (size_t)Bsz * Ssz * KC;     // 25,165,824
constexpr size_t WCD = (size_t)Dsz * KC;           // 3,145,728

typedef __attribute__((ext_vector_type(8))) short bf16x8;
typedef __attribute__((ext_vector_type(4))) float f32x4;

// ---------- helpers ----------
__device__ __forceinline__ unsigned short f2bf_rn(float f) {
    unsigned int u = __float_as_uint(f);
    return (unsigned short)((u + 0x7FFFu + ((u >> 16) & 1u)) >> 16);
}
__device__ __forceinline__ float bf2f(unsigned short h) {
    return __uint_as_float(((unsigned int)h) << 16);
}
__device__ __forceinline__ void bf_split(float f, unsigned short& hi, unsigned short& lo) {
    hi = f2bf_rn(f);
    lo = f2bf_rn(f - bf2f(hi));
}
__device__ __forceinline__ void gload16(const unsigned short* g, unsigned short* l) {
    __builtin_amdgcn_global_load_lds(
        (const __attribute__((address_space(1))) unsigned int*)g,
        (__attribute__((address_space(3))) unsigned int*)l, 16, 0, 0);
}
__device__ __forceinline__ bf16x8 gfrag(const unsigned short* g) {
    return *reinterpret_cast<const bf16x8*>(g);
}
__device__ __forceinline__ void make8(float4 a, float4 b, bf16x8& hi8, bf16x8& lo8) {
    float v[8] = {a.x, a.y, a.z, a.w, b.x, b.y, b.z, b.w};
    #pragma unroll
    for (int i = 0; i < 8; ++i) {
        unsigned short h, l;
        bf_split(v[i], h, l);
        hi8[i] = (short)h; lo8[i] = (short)l;
    }
}

// Stage a row-major tile into linear LDS with source-side chunk swizzle (flash path).
template<int LOGC, int NISS>
__device__ __forceinline__ void stage_tile(const unsigned short* __restrict__ g, long rowStride,
                                           unsigned short* lbase, int t) {
    const int wid = t >> 6;
    #pragma unroll
    for (int i = 0; i < NISS; ++i) {
        int slot = i * 256 + t;
        int r = slot >> LOGC;
        int c = slot & ((1 << LOGC) - 1);
        int cs = (c ^ (r & 7)) & ((1 << LOGC) - 1);
        gload16(g + (long)r * rowStride + cs * 8, lbase + (i * 256 + wid * 64) * 8);
    }
}
template<int ROWLEN>
__device__ __forceinline__ bf16x8 fragR(const unsigned short* buf, int row, int ks, int lane) {
    int c = ks * 4 + (lane >> 4);
    int cs = (c ^ (row & 7)) & (ROWLEN / 8 - 1);
    return *reinterpret_cast<const bf16x8*>(buf + row * ROWLEN + cs * 8);
}

// ---------- split kernels (concat layout) ----------
// inputs -> concat A' [8192][3072] = [hi | hi | lo]
__global__ __launch_bounds__(256)
void split_inputs(const float* __restrict__ q, const float* __restrict__ k,
                  const float* __restrict__ v,
                  unsigned short* __restrict__ Aq, unsigned short* __restrict__ Ak,
                  unsigned short* __restrict__ Av)
{
    const int job = blockIdx.y;
    const float* src = (job == 0) ? q : (job == 1) ? k : v;
    unsigned short* dst = (job == 0) ? Aq : (job == 1) ? Ak : Av;
    int idx4 = blockIdx.x * 256 + threadIdx.x;
    int row = idx4 >> 8;
    int col = (idx4 & 255) * 4;
    float4 v4 = reinterpret_cast<const float4*>(src)[idx4];
    ushort4 h, l;
    bf_split(v4.x, h.x, l.x);
    bf_split(v4.y, h.y, l.y);
    bf_split(v4.z, h.z, l.z);
    bf_split(v4.w, h.w, l.w);
    unsigned short* rp = dst + (size_t)row * KC + col;
    *reinterpret_cast<ushort4*>(rp)        = h;
    *reinterpret_cast<ushort4*>(rp + 1024) = h;
    *reinterpret_cast<ushort4*>(rp + 2048) = l;
}

// weights: jobs 0-2 -> concat W' [1024][3072] = [hi | lo | hi]; job 3 -> wo_hi/wo_lo
__global__ __launch_bounds__(256)
void split_weights(const float* __restrict__ Wq, const float* __restrict__ Wk,
                   const float* __restrict__ Wv, const float* __restrict__ Wo,
                   unsigned short* __restrict__ Wc,
                   unsigned short* __restrict__ wo_hi, unsigned short* __restrict__ wo_lo)
{
    const int job = blockIdx.y;
    const float* src = (job == 0) ? Wq : (job == 1) ? Wk : (job == 2) ? Wv : Wo;
    int idx4 = blockIdx.x * 256 + threadIdx.x;
    float4 v4 = reinterpret_cast<const float4*>(src)[idx4];
    ushort4 h, l;
    bf_split(v4.x, h.x, l.x);
    bf_split(v4.y, h.y, l.y);
    bf_split(v4.z, h.z, l.z);
    bf_split(v4.w, h.w, l.w);
    if (job < 3) {
        int row = idx4 >> 8;
        int col = (idx4 & 255) * 4;
        unsigned short* rp = Wc + (size_t)job * WCD + (size_t)row * KC + col;
        *reinterpret_cast<ushort4*>(rp)        = h;
        *reinterpret_cast<ushort4*>(rp + 1024) = l;
        *reinterpret_cast<ushort4*>(rp + 2048) = h;
    } else {
        reinterpret_cast<ushort4*>(wo_hi)[idx4] = h;
        reinterpret_cast<ushort4*>(wo_lo)[idx4] = l;
    }
}

// ---------- pipelined GEMM v2 for QKV ----------
// 256x128 tile, BK=64, 512 threads (8 waves = 4M x 2N), ring-3 LDS (144 KB),
// grid 768 = 3.0 full-GPU rounds. Stage tile kt+2 (3+3 issues across 2 phases);
// vmcnt(6) at tile boundary -> tile kt+1 (issued 2 tiles back) guaranteed resident.
// LDS per buf: A [256 r][64 k] 32KB + B [128 r][64 k] 16KB; chunk swizzle c^(r&7).
__global__ __launch_bounds__(512, 1)
void gemm_qkv_p2(const unsigned short* __restrict__ Aq, const unsigned short* __restrict__ Ak,
                 const unsigned short* __restrict__ Av, const unsigned short* __restrict__ Wc,
                 const float* __restrict__ bq, const float* __restrict__ bk, const float* __restrict__ bv,
                 unsigned short* __restrict__ qh_hi, unsigned short* __restrict__ qh_lo,
                 unsigned short* __restrict__ kh_hi, unsigned short* __restrict__ kh_lo,
                 unsigned short* __restrict__ vt_hi, unsigned short* __restrict__ vt_lo,
                 unsigned short* __restrict__ ag_hi, unsigned short* __restrict__ ag_lo)
{
    __shared__ unsigned short lds3[3 * 24576];   // 3 x (A 32KB + B 16KB) = 144 KB

    const int t = threadIdx.x, lane = t & 63, wid = t >> 6;
    const int al15 = lane & 15, g4 = lane >> 4;
    const int wr = wid >> 1, wc = wid & 1;       // wave grid 4M x 2N

    const int id = blockIdx.x;
    const int z = id >> 8, rem = id & 255;
    const int xcd = rem & 7, slot = rem >> 3;    // xcd co-location (id%8 == xcd)
    const int m0 = (xcd * 4 + (slot >> 3)) * 256;
    const int n0 = (slot & 7) * 128;

    const unsigned short* A = (z == 0) ? Aq : (z == 1) ? Ak : Av;
    const unsigned short* B = Wc + (size_t)z * WCD;
    const float* bias = (z == 0) ? bq : (z == 1) ? bk : bv;
    unsigned short* Chi = (z == 0) ? qh_hi : (z == 1) ? kh_hi : vt_hi;
    unsigned short* Clo = (z == 0) ? qh_lo : (z == 1) ? kh_lo : vt_lo;

    // staging offsets: slot s = i*512 + t; r = s>>3, chunk cp = s&7; src chunk = cp ^ (r&7)
    size_t asrc[4], bsrc[2];
    int dsto[4];
    #pragma unroll
    for (int i = 0; i < 4; ++i) {
        int sl = i * 512 + t;
        int r = sl >> 3, cp = sl & 7;
        int c = cp ^ (r & 7);
        asrc[i] = (size_t)(m0 + r) * KC + c * 8;
        dsto[i] = (i * 512 + wid * 64) * 8;
    }
    #pragma unroll
    for (int i = 0; i < 2; ++i) {
        int sl = i * 512 + t;
        int r = sl >> 3, cp = sl & 7;
        int c = cp ^ (r & 7);
        bsrc[i] = (size_t)(n0 + r) * KC + c * 8;
    }

    f32x4 acc[4][4];
    #pragma unroll
    for (int i = 0; i < 4; ++i)
        #pragma unroll
        for (int j = 0; j < 4; ++j)
            acc[i][j] = f32x4{0.f, 0.f, 0.f, 0.f};

    constexpr int NT = KC / 64;   // 48 K-tiles

    // prologue: stage tiles 0,1 (6 issues each); ensure tile 0 resident
    #pragma unroll
    for (int kt0 = 0; kt0 < 2; ++kt0) {
        unsigned short* buf = lds3 + kt0 * 24576;
        #pragma unroll
        for (int i = 0; i < 4; ++i)
            gload16(A + asrc[i] + kt0 * 64, buf + dsto[i]);
        #pragma unroll
        for (int i = 0; i < 2; ++i)
            gload16(B + bsrc[i] + kt0 * 64, buf + 16384 + dsto[i]);
    }
    asm volatile("s_waitcnt vmcnt(6)" ::: "memory");
    __builtin_amdgcn_s_barrier();

    #pragma unroll 1
    for (int kt = 0; kt < NT; ++kt) {
        const unsigned short* bufA = lds3 + (kt % 3) * 24576;
        const unsigned short* bufB = bufA + 16384;
        unsigned short* sbuf = lds3 + ((kt + 2) % 3) * 24576;
        const bool st = (kt + 2) < NT;
        const size_t koff = (size_t)(kt + 2) * 64;

        // ---- phase 1 (ks=0): frags + 3 A-stage issues ----
        bf16x8 af[4], bf[4];
        #pragma unroll
        for (int nf = 0; nf < 4; ++nf) {
            int row = wc * 64 + nf * 16 + al15;
            int cs = g4 ^ (row & 7);
            bf[nf] = *reinterpret_cast<const bf16x8*>(bufB + row * 64 + cs * 8);
        }
        #pragma unroll
        for (int mf = 0; mf < 4; ++mf) {
            int row = wr * 64 + mf * 16 + al15;
            int cs = g4 ^ (row & 7);
            af[mf] = *reinterpret_cast<const bf16x8*>(bufA + row * 64 + cs * 8);
        }
        if (st) {
            #pragma unroll
            for (int i = 0; i < 3; ++i)
                gload16(A + asrc[i] + koff, sbuf + dsto[i]);
        }
        __builtin_amdgcn_s_barrier();
        asm volatile("s_waitcnt lgkmcnt(0)" ::: "memory");
        __builtin_amdgcn_s_setprio(1);
        #pragma unroll
        for (int mf = 0; mf < 4; ++mf)
            #pragma unroll
            for (int nf = 0; nf < 4; ++nf)
                acc[mf][nf] = __builtin_amdgcn_mfma_f32_16x16x32_bf16(af[mf], bf[nf], acc[mf][nf], 0, 0, 0);
        __builtin_amdgcn_s_setprio(0);
        __builtin_amdgcn_s_barrier();

        // ---- phase 2 (ks=1): frags + remaining 3 stage issues; boundary vmcnt ----
        #pragma unroll
        for (int nf = 0; nf < 4; ++nf) {
            int row = wc * 64 + nf * 16 + al15;
            int cs = (4 + g4) ^ (row & 7);
            bf[nf] = *reinterpret_cast<const bf16x8*>(bufB + row * 64 + cs * 8);
        }
        #pragma unroll
        for (int mf = 0; mf < 4; ++mf) {
            int row = wr * 64 + mf * 16 + al15;
            int cs = (4 + g4) ^ (row & 7);
            af[mf] = *reinterpret_cast<const bf16x8*>(bufA + row * 64 + cs * 8);
        }
        if (st) {
            gload16(A + asrc[3] + koff, sbuf + dsto[3]);
            #pragma unroll
            for (int i = 0; i < 2; ++i)
                gload16(B + bsrc[i] + koff, sbuf + 16384 + dsto[i]);
        }
        if (kt < NT - 2)
            asm volatile("s_waitcnt vmcnt(6)" ::: "memory");
        else if (kt == NT - 2)
            asm volatile("s_waitcnt vmcnt(0)" ::: "memory");
        __builtin_amdgcn_s_barrier();
        asm volatile("s_waitcnt lgkmcnt(0)" ::: "memory");
        __builtin_amdgcn_s_setprio(1);
        #pragma unroll
        for (int mf = 0; mf < 4; ++mf)
            #pragma unroll
            for (int nf = 0; nf < 4; ++nf)
                acc[mf][nf] = __builtin_amdgcn_mfma_f32_16x16x32_bf16(af[mf], bf[nf], acc[mf][nf], 0, 0, 0);
        __builtin_amdgcn_s_setprio(0);
        __builtin_amdgcn_s_barrier();
    }

    // ---- epilogue: z-dependent layouts + fused agent pooling (z==0) ----
    #pragma unroll
    for (int mf = 0; mf < 4; ++mf) {
        #pragma unroll
        for (int nf = 0; nf < 4; ++nf) {
            const int n = n0 + wc * 64 + nf * 16 + al15;
            const float bval = bias[n];
            float psum = 0.f;
            #pragma unroll
            for (int j = 0; j < 4; ++j) {
                const int m = m0 + wr * 64 + mf * 16 + (g4 << 2) + j;
                float val = acc[mf][nf][j] + bval;
                psum += val;
                const int b = m >> 11, s = m & (Ssz - 1);
                const int h = n >> 6, c = n & (dh - 1);
                size_t idx;
                if (z == 0)
                    idx = (size_t)(b * Hn + h) * 131072
                        + (((s >> 4) * 2 + (c >> 5)) << 9)
                        + (((c >> 3) & 3) << 7) + ((s & 15) << 3) + (c & 7);
                else if (z == 1)
                    idx = (((size_t)(b * Hn + h)) * Ssz + s) * dh + c;
                else
                    idx = (((size_t)(b * Hn + h)) * dh + c) * Ssz + s;
                unsigned short hi, lo;
                bf_split(val, hi, lo);
                Chi[idx] = hi; Clo[idx] = lo;
            }
            if (z == 0) {
                psum += __shfl_xor(psum, 16);
                if (((lane >> 4) & 1) == 0) {
                    const float agv = psum * 0.125f;
                    const int mrow = m0 + wr * 64 + mf * 16;
                    const int b = mrow >> 11, sRow = mrow & (Ssz - 1);
                    const int h = n >> 6, c = n & (dh - 1);
                    const int a = (sRow >> 3) + ((lane >> 5) & 1);
                    const int bh_ = b * Hn + h;
                    unsigned short hi, lo;
                    bf_split(agv, hi, lo);
                    const size_t oidx = (size_t)bh_ * 16384
                        + (((a >> 4) * 2 + (c >> 5)) << 9) + (((c >> 3) & 3) << 7)
                        + ((a & 15) << 3) + (c & 7);
                    ag_hi[oidx] = hi; ag_lo[oidx] = lo;
                }
            }
        }
    }
}

// ---------- old-structure GEMM (output projection only) ----------
#define MT 128
#define BKm 32

__device__ __forceinline__ bf16x8 lds_frag(const unsigned short* buf, int baseRow, int lane) {
    int row = baseRow + (lane & 15);
    int c = lane >> 4;
    int idx = row * 32 + ((c ^ ((row >> 1) & 3)) << 3);
    return *reinterpret_cast<const bf16x8*>(buf + idx);
}

__global__ __launch_bounds__(256, 2)
void gemm_out(const unsigned short* __restrict__ Ahi_, const unsigned short* __restrict__ Alo_,
              const unsigned short* __restrict__ Bhi_, const unsigned short* __restrict__ Blo_,
              const float* __restrict__ bias, float* __restrict__ Cf)
{
    const int rem = blockIdx.x & 511;
    const int xcd = rem & 7, slot = rem >> 3;
    const int m0 = (xcd * 8 + (slot >> 3)) * MT;
    const int n0 = (slot & 7) * MT;

    __shared__ unsigned short lds[4 * 4096];
    const int t = threadIdx.x;
    const int lane = t & 63, wid = t >> 6;
    const int wr = wid >> 1, wc = wid & 1;
    const int srow0 = t >> 2;
    const int x4 = t & 3;
    const int ldsBase0 = (wid * 64) * 8;
    const int ldsBase1 = (256 + wid * 64) * 8;
    f32x4 acc[4][4];
    #pragma unroll
    for (int i = 0; i < 4; ++i)
        #pragma unroll
        for (int j = 0; j < 4; ++j)
            acc[i][j] = f32x4{0.f, 0.f, 0.f, 0.f};
    const unsigned short* gA[2] = {Ahi_, Alo_};
    const unsigned short* gB[2] = {Bhi_, Blo_};
    for (int k0 = 0; k0 < Dsz; k0 += BKm) {
        #pragma unroll
        for (int hb = 0; hb < 2; ++hb) {
            {
                const unsigned short* G = gA[hb];
                int r0 = srow0, r1 = srow0 + 64;
                int c0 = x4 ^ ((r0 >> 1) & 3);
                int c1 = x4 ^ ((r1 >> 1) & 3);
                gload16(G + (size_t)(m0 + r0) * Dsz + k0 + c0 * 8, lds + hb * 4096 + ldsBase0);
                gload16(G + (size_t)(m0 + r1) * Dsz + k0 + c1 * 8, lds + hb * 4096 + ldsBase1);
            }
            {
                const unsigned short* G = gB[hb];
                int r0 = srow0, r1 = srow0 + 64;
                int c0 = x4 ^ ((r0 >> 1) & 3);
                int c1 = x4 ^ ((r1 >> 1) & 3);
                gload16(G + (size_t)(n0 + r0) * Dsz + k0 + c0 * 8, lds + (2 + hb) * 4096 + ldsBase0);
                gload16(G + (size_t)(n0 + r1) * Dsz + k0 + c1 * 8, lds + (2 + hb) * 4096 + ldsBase1);
            }
        }
        __syncthreads();
        bf16x8 ah[4], al[4], bh[4], bl[4];
        #pragma unroll
        for (int mi = 0; mi < 4; ++mi) {
            ah[mi] = lds_frag(lds + 0 * 4096, wr * 64 + mi * 16, lane);
            al[mi] = lds_frag(lds + 1 * 4096, wr * 64 + mi * 16, lane);
        }
        #pragma unroll
        for (int ni = 0; ni < 4; ++ni) {
            bh[ni] = lds_frag(lds + 2 * 4096, wc * 64 + ni * 16, lane);
            bl[ni] = lds_frag(lds + 3 * 4096, wc * 64 + ni * 16, lane);
        }
        #pragma unroll
        for (int mi = 0; mi < 4; ++mi)
            #pragma unroll
            for (int ni = 0; ni < 4; ++ni) {
                acc[mi][ni] = __builtin_amdgcn_mfma_f32_16x16x32_bf16(ah[mi], bh[ni], acc[mi][ni], 0, 0, 0);
                acc[mi][ni] = __builtin_amdgcn_mfma_f32_16x16x32_bf16(ah[mi], bl[ni], acc[mi][ni], 0, 0, 0);
                acc[mi][ni] = __builtin_amdgcn_mfma_f32_16x16x32_bf16(al[mi], bh[ni], acc[mi][ni], 0, 0, 0);
            }
        __syncthreads();
    }

    #pragma unroll
    for (int mi = 0; mi < 4; ++mi) {
        #pragma unroll
        for (int ni = 0; ni < 4; ++ni) {
            const int n = n0 + wc * 64 + ni * 16 + (lane & 15);
            const float bval = bias[n];
            #pragma unroll
            for (int j = 0; j < 4; ++j) {
                const int m = m0 + wr * 64 + mi * 16 + ((lane >> 4) << 2) + j;
                Cf[(size_t)m * Dsz + n] = acc[mi][ni][j] + bval;
            }
        }
    }
}

// ---------- flash stage-1: XCD-co-located flat grid (id&63 = bh) ----------
__global__ __launch_bounds__(256, 3)
void flash1(const unsigned short* __restrict__ ag_hi, const unsigned short* __restrict__ ag_lo,
            const unsigned short* __restrict__ kh_hi, const unsigned short* __restrict__ kh_lo,
            const unsigned short* __restrict__ vt_hi_g, const unsigned short* __restrict__ vt_lo_g,
            unsigned short* __restrict__ avt_hi, unsigned short* __restrict__ avt_lo)
{
    __shared__ unsigned short lds[24576];
    unsigned short* kth = lds;
    unsigned short* ktl = lds + 4096;
    unsigned short* vth = lds + 8192;
    unsigned short* vtl = lds + 12288;
    const int t = threadIdx.x;
    const int lane = t & 63, w = t >> 6;
    const int al15 = lane & 15, hi4 = lane >> 4;
    unsigned short* pwh = lds + 16384 + w * 2048;
    unsigned short* pwl = pwh + 1024;

    const int bh = blockIdx.x & 63;
    const int a0 = (blockIdx.x >> 6) * 64;

    bf16x8 bqh[2], bql[2];
    {
        const size_t abase = (size_t)bh * 16384 + (size_t)((a0 >> 4) + w) * 1024;
        #pragma unroll
        for (int ks = 0; ks < 2; ++ks) {
            bqh[ks] = gfrag(ag_hi + abase + ks * 512 + lane * 8);
            bql[ks] = gfrag(ag_lo + abase + ks * 512 + lane * 8);
        }
    }

    f32x4 O[4];
    #pragma unroll
    for (int i = 0; i < 4; ++i) O[i] = f32x4{0.f, 0.f, 0.f, 0.f};
    float m_run = -INFINITY, l_run = 0.f;

    for (int s0 = 0; s0 < Ssz; s0 += 64) {
        stage_tile<3, 2>(kh_hi + ((size_t)bh * Ssz + s0) * dh, dh, kth, t);
        stage_tile<3, 2>(kh_lo + ((size_t)bh * Ssz + s0) * dh, dh, ktl, t);
        stage_tile<3, 2>(vt_hi_g + (size_t)bh * dh * Ssz + s0, Ssz, vth, t);
        stage_tile<3, 2>(vt_lo_g + (size_t)bh * dh * Ssz + s0, Ssz, vtl, t);
        __syncthreads();

        f32x4 sc[4];
        #pragma unroll
        for (int si = 0; si < 4; ++si) sc[si] = f32x4{0.f, 0.f, 0.f, 0.f};
        #pragma unroll
        for (int si = 0; si < 4; ++si)
            #pragma unroll
            for (int ks = 0; ks < 2; ++ks) {
                bf16x8 ah = fragR<64>(kth, si * 16 + al15, ks, lane);
                bf16x8 al = fragR<64>(ktl, si * 16 + al15, ks, lane);
                sc[si] = __builtin_amdgcn_mfma_f32_16x16x32_bf16(ah, bqh[ks], sc[si], 0, 0, 0);
                sc[si] = __builtin_amdgcn_mfma_f32_16x16x32_bf16(ah, bql[ks], sc[si], 0, 0, 0);
                sc[si] = __builtin_amdgcn_mfma_f32_16x16x32_bf16(al, bqh[ks], sc[si], 0, 0, 0);
            }

        float tmax = -INFINITY;
        #pragma unroll
        for (int si = 0; si < 4; ++si)
            #pragma unroll
            for (int j = 0; j < 4; ++j) {
                sc[si][j] *= 0.125f;
                tmax = fmaxf(tmax, sc[si][j]);
            }
        tmax = fmaxf(tmax, __shfl_xor(tmax, 16));
        tmax = fmaxf(tmax, __shfl_xor(tmax, 32));
        float newm = fmaxf(m_run, tmax);
        float fac = __expf(m_run - newm);
        float tsum = 0.f;
        #pragma unroll
        for (int si = 0; si < 4; ++si)
            #pragma unroll
            for (int j = 0; j < 4; ++j) {
                float p = __expf(sc[si][j] - newm);
                sc[si][j] = p;
                tsum += p;
            }
        tsum += __shfl_xor(tsum, 16);
        tsum += __shfl_xor(tsum, 32);
        l_run = l_run * fac + tsum;
        m_run = newm;

        #pragma unroll
        for (int si = 0; si < 4; ++si) {
            ushort4 h4, l4;
            bf_split(sc[si][0], h4.x, l4.x);
            bf_split(sc[si][1], h4.y, l4.y);
            bf_split(sc[si][2], h4.z, l4.z);
            bf_split(sc[si][3], h4.w, l4.w);
            int baseS = si * 16 + (hi4 << 2);
            int addr = al15 * 64 + (baseS ^ ((al15 & 7) << 3));
            *reinterpret_cast<ushort4*>(pwh + addr) = h4;
            *reinterpret_cast<ushort4*>(pwl + addr) = l4;
        }

        float fj[4];
        #pragma unroll
        for (int j = 0; j < 4; ++j) fj[j] = __shfl(fac, (hi4 << 2) + j);
        #pragma unroll
        for (int di = 0; di < 4; ++di)
            #pragma unroll
            for (int j = 0; j < 4; ++j) O[di][j] *= fj[j];

        #pragma unroll
        for (int ks = 0; ks < 2; ++ks) {
            bf16x8 pah = fragR<64>(pwh, al15, ks, lane);
            bf16x8 pal = fragR<64>(pwl, al15, ks, lane);
            #pragma unroll
            for (int di = 0; di < 4; ++di) {
                bf16x8 vh = fragR<64>(vth, di * 16 + al15, ks, lane);
                bf16x8 vl = fragR<64>(vtl, di * 16 + al15, ks, lane);
                O[di] = __builtin_amdgcn_mfma_f32_16x16x32_bf16(pah, vh, O[di], 0, 0, 0);
                O[di] = __builtin_amdgcn_mfma_f32_16x16x32_bf16(pah, vl, O[di], 0, 0, 0);
                O[di] = __builtin_amdgcn_mfma_f32_16x16x32_bf16(pal, vh, O[di], 0, 0, 0);
            }
        }
        __syncthreads();
    }

    float lj[4];
    #pragma unroll
    for (int j = 0; j < 4; ++j) lj[j] = __shfl(l_run, (hi4 << 2) + j);
    #pragma unroll
    for (int di = 0; di < 4; ++di) {
        ushort4 h4, l4;
        #pragma unroll
        for (int j = 0; j < 4; ++j) {
            float val = O[di][j] / lj[j];
            unsigned short hi, lo;
            bf_split(val, hi, lo);
            ((unsigned short*)&h4)[j] = hi;
            ((unsigned short*)&l4)[j] = lo;
        }
        const size_t oidx = (size_t)bh * 16384
            + (size_t)(di * 8 + (a0 >> 5) + (w >> 1)) * 512
            + (size_t)((2 * w + (hi4 >> 1)) & 3) * 128
            + al15 * 8 + (hi4 & 1) * 4;
        *reinterpret_cast<ushort4*>(avt_hi + oidx) = h4;
        *reinterpret_cast<ushort4*>(avt_lo + oidx) = l4;
    }
}

// ---------- flash stage-2: XCD-co-located flat grid (id&63 = bh) ----------
__global__ __launch_bounds__(256, 2)
void flash2(const unsigned short* __restrict__ qh_hi, const unsigned short* __restrict__ qh_lo,
            const unsigned short* __restrict__ ag_hi, const unsigned short* __restrict__ ag_lo,
            const unsigned short* __restrict__ avt_hi, const unsigned short* __restrict__ avt_lo,
            float* __restrict__ q_attn,
            unsigned short* __restrict__ xo_hi, unsigned short* __restrict__ xo_lo)
{
    __shared__ float plds[4][4096];

    const int t = threadIdx.x, lane = t & 63, w = t >> 6;
    const int al15 = lane & 15, hi4 = lane >> 4;
    const int bh = blockIdx.x & 63;
    const int s0 = (blockIdx.x >> 6) * 64;
    float* P = plds[w];

    bf16x8 bqh[2], bql[2];
    {
        const size_t qbase = (size_t)bh * 131072 + (size_t)((s0 >> 4) + w) * 1024;
        #pragma unroll
        for (int ks = 0; ks < 2; ++ks) {
            bqh[ks] = gfrag(qh_hi + qbase + ks * 512 + lane * 8);
            bql[ks] = gfrag(qh_lo + qbase + ks * 512 + lane * 8);
        }
    }

    const unsigned short* agh = ag_hi + (size_t)bh * 16384;
    const unsigned short* agl = ag_lo + (size_t)bh * 16384;
    f32x4 acc[16];
    #pragma unroll
    for (int ai = 0; ai < 16; ++ai) acc[ai] = f32x4{0.f, 0.f, 0.f, 0.f};
    #pragma unroll
    for (int ai = 0; ai < 16; ++ai)
        #pragma unroll
        for (int ks = 0; ks < 2; ++ks) {
            bf16x8 ah = gfrag(agh + (ai * 2 + ks) * 512 + lane * 8);
            bf16x8 al = gfrag(agl + (ai * 2 + ks) * 512 + lane * 8);
            acc[ai] = __builtin_amdgcn_mfma_f32_16x16x32_bf16(ah, bqh[ks], acc[ai], 0, 0, 0);
            acc[ai] = __builtin_amdgcn_mfma_f32_16x16x32_bf16(ah, bql[ks], acc[ai], 0, 0, 0);
            acc[ai] = __builtin_amdgcn_mfma_f32_16x16x32_bf16(al, bqh[ks], acc[ai], 0, 0, 0);
        }

    float mx = -INFINITY;
    #pragma unroll
    for (int ai = 0; ai < 16; ++ai)
        #pragma unroll
        for (int j = 0; j < 4; ++j) {
            acc[ai][j] *= 0.125f;
            mx = fmaxf(mx, acc[ai][j]);
        }
    mx = fmaxf(mx, __shfl_xor(mx, 16));
    mx = fmaxf(mx, __shfl_xor(mx, 32));
    float sum = 0.f;
    #pragma unroll
    for (int ai = 0; ai < 16; ++ai)
        #pragma unroll
        for (int j = 0; j < 4; ++j) {
            float p = __expf(acc[ai][j] - mx);
            acc[ai][j] = p;
            sum += p;
        }
    sum += __shfl_xor(sum, 16);
    sum += __shfl_xor(sum, 32);
    const float inv = 1.0f / sum;

    #pragma unroll
    for (int ai = 0; ai < 16; ++ai) {
        float4 o;
        o.x = acc[ai][0] * inv; o.y = acc[ai][1] * inv;
        o.z = acc[ai][2] * inv; o.w = acc[ai][3] * inv;
        int pos4 = (ai * 4 + hi4) ^ (al15 & 7);
        *reinterpret_cast<float4*>(P + al15 * 256 + pos4 * 4) = o;
    }

    {
        float* qbase = q_attn + ((size_t)bh * Ssz + s0 + w * 16) * An;
        #pragma unroll
        for (int r = 0; r < 16; ++r) {
            float4 f = *reinterpret_cast<const float4*>(P + r * 256 + ((lane ^ (r & 7)) * 4));
            *reinterpret_cast<float4*>(qbase + r * An + lane * 4) = f;
        }
    }

    const unsigned short* avh_b = avt_hi + (size_t)bh * 16384;
    const unsigned short* avl_b = avt_lo + (size_t)bh * 16384;
    f32x4 O[4];
    #pragma unroll
    for (int i = 0; i < 4; ++i) O[i] = f32x4{0.f, 0.f, 0.f, 0.f};
    #pragma unroll
    for (int ks = 0; ks < 8; ++ks) {
        int p4 = ks * 8 + hi4 * 2;
        float4 fa = *reinterpret_cast<const float4*>(P + al15 * 256 + ((p4 ^ (al15 & 7)) * 4));
        float4 fb = *reinterpret_cast<const float4*>(P + al15 * 256 + (((p4 + 1) ^ (al15 & 7)) * 4));
        bf16x8 pah, pal;
        make8(fa, fb, pah, pal);
        #pragma unroll
        for (int di = 0; di < 4; ++di) {
            bf16x8 avh = gfrag(avh_b + (di * 8 + ks) * 512 + lane * 8);
            bf16x8 avl = gfrag(avl_b + (di * 8 + ks) * 512 + lane * 8);
            O[di] = __builtin_amdgcn_mfma_f32_16x16x32_bf16(pah, avh, O[di], 0, 0, 0);
            O[di] = __builtin_amdgcn_mfma_f32_16x16x32_bf16(pah, avl, O[di], 0, 0, 0);
            O[di] = __builtin_amdgcn_mfma_f32_16x16x32_bf16(pal, avh, O[di], 0, 0, 0);
        }
    }

    const int b = bh >> 4, h = bh & (Hn - 1);
    #pragma unroll
    for (int di = 0; di < 4; ++di)
        #pragma unroll
        for (int j = 0; j < 4; ++j) {
            float val = O[di][j];
            int sG = s0 + w * 16 + (hi4 << 2) + j;
            int dfull = h * dh + di * 16 + al15;
            size_t idx = ((size_t)b * Ssz + sG) * Dsz + dfull;
            unsigned short hi, lo;
            bf_split(val, hi, lo);
            xo_hi[idx] = hi; xo_lo[idx] = lo;
        }
}

extern "C" void kernel_launch(void* const* d_in, const int* in_sizes, int n_in,
                              void* d_out, int out_size, void* d_ws, size_t ws_size,
                              hipStream_t stream)
{
    const float* q  = (const float*)d_in[0];
    const float* k  = (const float*)d_in[1];
    const float* v  = (const float*)d_in[2];
    const float* Wq = (const float*)d_in[3];
    const float* bq = (const float*)d_in[4];
    const float* Wk = (const float*)d_in[5];
    const float* bk = (const float*)d_in[6];
    const float* Wv = (const float*)d_in[7];
    const float* bv = (const float*)d_in[8];
    const float* Wo = (const float*)d_in[9];
    const float* bo = (const float*)d_in[10];

    float* out    = (float*)d_out;
    float* q_attn = out + BSD;

    unsigned short* u = (unsigned short*)d_ws;
    unsigned short* Aq    = u;                  // concat A' [8192][3072]
    unsigned short* Ak    = Aq + ACD;
    unsigned short* Av    = Ak + ACD;
    unsigned short* Wc    = Av + ACD;           // concat W' [3][1024][3072]
    unsigned short* wo_hi = Wc + 3 * WCD;       // Wo split
    unsigned short* wo_lo = wo_hi + DD;
    unsigned short* qh_hi = wo_lo + DD;         // qh TILE layout
    unsigned short* qh_lo = qh_hi + BSD;
    unsigned short* kh_hi = qh_lo + BSD;        // [B,H,S,dh]
    unsigned short* kh_lo = kh_hi + BSD;
    unsigned short* vt_hi = kh_lo + BSD;        // [B,H,dh,S]
    unsigned short* vt_lo = vt_hi + BSD;
    unsigned short* xo_hi = vt_lo + BSD;        // out_h split [B,S,D]
    unsigned short* xo_lo = xo_hi + BSD;
    unsigned short* ag_hi = xo_lo + BSD;        // agents TILE
    unsigned short* ag_lo = ag_hi + AGD;
    unsigned short* avt_hi = ag_lo + AGD;       // avt TILE
    unsigned short* avt_lo = avt_hi + AGD;

    // 1) splits (concat layout)
    split_inputs<<<dim3(BSD / 1024, 3), 256, 0, stream>>>(q, k, v, Aq, Ak, Av);
    split_weights<<<dim3(DD / 1024, 4), 256, 0, stream>>>(Wq, Wk, Wv, Wo, Wc, wo_hi, wo_lo);

    // 2) QKV projections — pipelined 256x128 GEMM (768 blocks = 3.0 rounds) + fused pooling
    gemm_qkv_p2<<<768, 512, 0, stream>>>(
        Aq, Ak, Av, Wc, bq, bk, bv,
        qh_hi, qh_lo, kh_hi, kh_lo, vt_hi, vt_lo, ag_hi, ag_lo);

    // 3) stage 1 flash
    flash1<<<256, 256, 0, stream>>>(
        ag_hi, ag_lo, kh_hi, kh_lo, vt_hi, vt_lo, avt_hi, avt_lo);

    // 4) stage 2 flash -> q_attn + out_h
    flash2<<<2048, 256, 0, stream>>>(
        qh_hi, qh_lo, ag_hi, ag_lo, avt_hi, avt_lo, q_attn, xo_hi, xo_lo);

    // 5) output projection
    gemm_out<<<512, 256, 0, stream>>>(
        xo_hi, xo_lo, wo_hi, wo_lo, bo, out);
}

// Round 15
// 402.901 us; speedup vs baseline: 1.2089x; 1.1138x over previous
//
#include <hip/hip_runtime.h>

// Problem constants
constexpr int Bsz = 4, Ssz = 2048, Dsz = 1024, Hn = 16, dh = 64, An = 256;
constexpr size_t BSD = (size_t)Bsz * Ssz * Dsz;    // 8,388,608
constexpr size_t DD  = (size_t)Dsz * Dsz;          // 1,048,576
constexpr size_t AGD = (size_t)Bsz * Hn * An * dh; // 1,048,576

typedef __attribute__((ext_vector_type(8))) short bf16x8;
typedef __attribute__((ext_vector_type(4))) float f32x4;

// ---------- helpers ----------
__device__ __forceinline__ unsigned short f2bf_rn(float f) {
    unsigned int u = __float_as_uint(f);
    return (unsigned short)((u + 0x7FFFu + ((u >> 16) & 1u)) >> 16);
}
__device__ __forceinline__ float bf2f(unsigned short h) {
    return __uint_as_float(((unsigned int)h) << 16);
}
__device__ __forceinline__ void bf_split(float f, unsigned short& hi, unsigned short& lo) {
    hi = f2bf_rn(f);
    lo = f2bf_rn(f - bf2f(hi));
}
__device__ __forceinline__ void gload16(const unsigned short* g, unsigned short* l) {
    __builtin_amdgcn_global_load_lds(
        (const __attribute__((address_space(1))) unsigned int*)g,
        (__attribute__((address_space(3))) unsigned int*)l, 16, 0, 0);
}
__device__ __forceinline__ bf16x8 gfrag(const unsigned short* g) {
    return *reinterpret_cast<const bf16x8*>(g);
}
__device__ __forceinline__ void make8(float4 a, float4 b, bf16x8& hi8, bf16x8& lo8) {
    float v[8] = {a.x, a.y, a.z, a.w, b.x, b.y, b.z, b.w};
    #pragma unroll
    for (int i = 0; i < 8; ++i) {
        unsigned short h, l;
        bf_split(v[i], h, l);
        hi8[i] = (short)h; lo8[i] = (short)l;
    }
}

// Stage a row-major tile into linear LDS with source-side chunk swizzle.
template<int LOGC, int NISS>
__device__ __forceinline__ void stage_tile(const unsigned short* __restrict__ g, long rowStride,
                                           unsigned short* lbase, int t) {
    const int wid = t >> 6;
    #pragma unroll
    for (int i = 0; i < NISS; ++i) {
        int slot = i * 256 + t;
        int r = slot >> LOGC;
        int c = slot & ((1 << LOGC) - 1);
        int cs = (c ^ (r & 7)) & ((1 << LOGC) - 1);
        gload16(g + (long)r * rowStride + cs * 8, lbase + (i * 256 + wid * 64) * 8);
    }
}
template<int ROWLEN>
__device__ __forceinline__ bf16x8 fragR(const unsigned short* buf, int row, int ks, int lane) {
    int c = ks * 4 + (lane >> 4);
    int cs = (c ^ (row & 7)) & (ROWLEN / 8 - 1);
    return *reinterpret_cast<const bf16x8*>(buf + row * ROWLEN + cs * 8);
}

// ---------- fused split kernels ----------
__device__ __forceinline__ void split4(const float* __restrict__ src,
                                       unsigned short* __restrict__ hi,
                                       unsigned short* __restrict__ lo, int i) {
    float4 v = reinterpret_cast<const float4*>(src)[i];
    ushort4 h, l;
    bf_split(v.x, h.x, l.x);
    bf_split(v.y, h.y, l.y);
    bf_split(v.z, h.z, l.z);
    bf_split(v.w, h.w, l.w);
    reinterpret_cast<ushort4*>(hi)[i] = h;
    reinterpret_cast<ushort4*>(lo)[i] = l;
}

// grid (BSD/1024, 3): q,k,v -> xq,xk,xv
__global__ __launch_bounds__(256)
void split_inputs(const float* __restrict__ q, const float* __restrict__ k,
                  const float* __restrict__ v,
                  unsigned short* __restrict__ xq_hi, unsigned short* __restrict__ xq_lo,
                  unsigned short* __restrict__ xk_hi, unsigned short* __restrict__ xk_lo,
                  unsigned short* __restrict__ xv_hi, unsigned short* __restrict__ xv_lo)
{
    const int job = blockIdx.y;
    const float* src = (job == 0) ? q : (job == 1) ? k : v;
    unsigned short* dh_ = (job == 0) ? xq_hi : (job == 1) ? xk_hi : xv_hi;
    unsigned short* dl_ = (job == 0) ? xq_lo : (job == 1) ? xk_lo : xv_lo;
    int i = blockIdx.x * 256 + threadIdx.x;
    split4(src, dh_, dl_, i);
}

// grid (DD/1024, 4): Wq,Wk,Wv,Wo -> w4 (+j*DD)
__global__ __launch_bounds__(256)
void split_weights(const float* __restrict__ Wq, const float* __restrict__ Wk,
                   const float* __restrict__ Wv, const float* __restrict__ Wo,
                   unsigned short* __restrict__ w_hi, unsigned short* __restrict__ w_lo)
{
    const int job = blockIdx.y;
    const float* src = (job == 0) ? Wq : (job == 1) ? Wk : (job == 2) ? Wv : Wo;
    int i = blockIdx.x * 256 + threadIdx.x;
    split4(src, w_hi + job * DD, w_lo + job * DD, i);
}

// ---------- split-bf16 MFMA GEMM core ----------
#define MT 128
#define BKm 32

__device__ __forceinline__ bf16x8 lds_frag(const unsigned short* buf, int baseRow, int lane) {
    int row = baseRow + (lane & 15);
    int c = lane >> 4;
    int idx = row * 32 + ((c ^ ((row >> 1) & 3)) << 3);
    return *reinterpret_cast<const bf16x8*>(buf + idx);
}

// GEMM body: expects `const int m0, n0` already defined in scope.
#define GEMM_BODY(Ahi, Alo, Bhi, Blo)                                                   \
    __shared__ unsigned short lds[4 * 4096];                                            \
    const int t = threadIdx.x;                                                          \
    const int lane = t & 63, wid = t >> 6;                                              \
    const int wr = wid >> 1, wc = wid & 1;                                              \
    const int srow0 = t >> 2;                                                           \
    const int x4 = t & 3;                                                               \
    const int ldsBase0 = (wid * 64) * 8;                                                \
    const int ldsBase1 = (256 + wid * 64) * 8;                                          \
    f32x4 acc[4][4];                                                                    \
    _Pragma("unroll")                                                                   \
    for (int i = 0; i < 4; ++i)                                                         \
        _Pragma("unroll")                                                               \
        for (int j = 0; j < 4; ++j)                                                     \
            acc[i][j] = f32x4{0.f, 0.f, 0.f, 0.f};                                      \
    const unsigned short* gA[2] = {Ahi, Alo};                                           \
    const unsigned short* gB[2] = {Bhi, Blo};                                           \
    for (int k0 = 0; k0 < Dsz; k0 += BKm) {                                             \
        _Pragma("unroll")                                                               \
        for (int hb = 0; hb < 2; ++hb) {                                                \
            {                                                                           \
                const unsigned short* G = gA[hb];                                       \
                int r0 = srow0, r1 = srow0 + 64;                                        \
                int c0 = x4 ^ ((r0 >> 1) & 3);                                          \
                int c1 = x4 ^ ((r1 >> 1) & 3);                                          \
                gload16(G + (size_t)(m0 + r0) * Dsz + k0 + c0 * 8, lds + hb * 4096 + ldsBase0); \
                gload16(G + (size_t)(m0 + r1) * Dsz + k0 + c1 * 8, lds + hb * 4096 + ldsBase1); \
            }                                                                           \
            {                                                                           \
                const unsigned short* G = gB[hb];                                       \
                int r0 = srow0, r1 = srow0 + 64;                                        \
                int c0 = x4 ^ ((r0 >> 1) & 3);                                          \
                int c1 = x4 ^ ((r1 >> 1) & 3);                                          \
                gload16(G + (size_t)(n0 + r0) * Dsz + k0 + c0 * 8, lds + (2 + hb) * 4096 + ldsBase0); \
                gload16(G + (size_t)(n0 + r1) * Dsz + k0 + c1 * 8, lds + (2 + hb) * 4096 + ldsBase1); \
            }                                                                           \
        }                                                                               \
        __syncthreads();                                                                \
        bf16x8 ah[4], al[4], bh[4], bl[4];                                              \
        _Pragma("unroll")                                                               \
        for (int mi = 0; mi < 4; ++mi) {                                                \
            ah[mi] = lds_frag(lds + 0 * 4096, wr * 64 + mi * 16, lane);                 \
            al[mi] = lds_frag(lds + 1 * 4096, wr * 64 + mi * 16, lane);                 \
        }                                                                               \
        _Pragma("unroll")                                                               \
        for (int ni = 0; ni < 4; ++ni) {                                                \
            bh[ni] = lds_frag(lds + 2 * 4096, wc * 64 + ni * 16, lane);                 \
            bl[ni] = lds_frag(lds + 3 * 4096, wc * 64 + ni * 16, lane);                 \
        }                                                                               \
        _Pragma("unroll")                                                               \
        for (int mi = 0; mi < 4; ++mi)                                                  \
            _Pragma("unroll")                                                           \
            for (int ni = 0; ni < 4; ++ni) {                                            \
                acc[mi][ni] = __builtin_amdgcn_mfma_f32_16x16x32_bf16(ah[mi], bh[ni], acc[mi][ni], 0, 0, 0); \
                acc[mi][ni] = __builtin_amdgcn_mfma_f32_16x16x32_bf16(ah[mi], bl[ni], acc[mi][ni], 0, 0, 0); \
                acc[mi][ni] = __builtin_amdgcn_mfma_f32_16x16x32_bf16(al[mi], bh[ni], acc[mi][ni], 0, 0, 0); \
            }                                                                           \
        __syncthreads();                                                                \
    }

// QKV merged projection: flat grid 1536, XCD-swizzled.
// z = id>>9. Within z: xcd = rem&7 owns m-panels [xcd*8, xcd*8+8), n fastest.
// z==0 additionally pools agents (fused pool_agent) from exact fp32 values.
__global__ __launch_bounds__(256, 2)
void gemm_qkv(const unsigned short* __restrict__ xq_hi, const unsigned short* __restrict__ xq_lo,
              const unsigned short* __restrict__ xk_hi, const unsigned short* __restrict__ xk_lo,
              const unsigned short* __restrict__ xv_hi, const unsigned short* __restrict__ xv_lo,
              const unsigned short* __restrict__ w_hi, const unsigned short* __restrict__ w_lo,
              const float* __restrict__ bq, const float* __restrict__ bk, const float* __restrict__ bv,
              unsigned short* __restrict__ qh_hi, unsigned short* __restrict__ qh_lo,
              unsigned short* __restrict__ kh_hi, unsigned short* __restrict__ kh_lo,
              unsigned short* __restrict__ vt_hi, unsigned short* __restrict__ vt_lo,
              unsigned short* __restrict__ ag_hi, unsigned short* __restrict__ ag_lo)
{
    const int id = blockIdx.x;
    const int z = id >> 9;
    const int rem = id & 511;
    const int xcd = rem & 7, slot = rem >> 3;
    const int m0 = (xcd * 8 + (slot >> 3)) * MT;
    const int n0 = (slot & 7) * MT;

    const unsigned short* Ahi = (z == 0) ? xq_hi : (z == 1) ? xk_hi : xv_hi;
    const unsigned short* Alo = (z == 0) ? xq_lo : (z == 1) ? xk_lo : xv_lo;
    const unsigned short* Bhi = w_hi + (size_t)z * DD;
    const unsigned short* Blo = w_lo + (size_t)z * DD;
    const float* bias = (z == 0) ? bq : (z == 1) ? bk : bv;
    unsigned short* Chi = (z == 0) ? qh_hi : (z == 1) ? kh_hi : vt_hi;
    unsigned short* Clo = (z == 0) ? qh_lo : (z == 1) ? kh_lo : vt_lo;

    GEMM_BODY(Ahi, Alo, Bhi, Blo)

    #pragma unroll
    for (int mi = 0; mi < 4; ++mi) {
        #pragma unroll
        for (int ni = 0; ni < 4; ++ni) {
            const int n = n0 + wc * 64 + ni * 16 + (lane & 15);
            const float bval = bias[n];
            float psum = 0.f;
            #pragma unroll
            for (int j = 0; j < 4; ++j) {
                const int m = m0 + wr * 64 + mi * 16 + ((lane >> 4) << 2) + j;
                float val = acc[mi][ni][j] + bval;
                psum += val;
                const int b = m >> 11, s = m & (Ssz - 1);
                const int h = n >> 6, c = n & (dh - 1);
                size_t idx;
                if (z == 0)
                    idx = (size_t)(b * Hn + h) * 131072
                        + (((s >> 4) * 2 + (c >> 5)) << 9)
                        + (((c >> 3) & 3) << 7) + ((s & 15) << 3) + (c & 7);
                else if (z == 1)
                    idx = (((size_t)(b * Hn + h)) * Ssz + s) * dh + c;
                else
                    idx = (((size_t)(b * Hn + h)) * dh + c) * Ssz + s;
                unsigned short hi, lo;
                bf_split(val, hi, lo);
                Chi[idx] = hi; Clo[idx] = lo;
            }
            if (z == 0) {
                // fused agent pooling: 16 rows of this fragment = 2 agents (8 rows each)
                psum += __shfl_xor(psum, 16);   // combine row groups 0-7 / 8-15
                if (((lane >> 4) & 1) == 0) {   // lane groups 0 (agent a) and 2 (agent a+1)
                    const float agv = psum * 0.125f;
                    const int mrow = m0 + wr * 64 + mi * 16;
                    const int b = mrow >> 11, sRow = mrow & (Ssz - 1);
                    const int h = n >> 6, c = n & (dh - 1);
                    const int a = (sRow >> 3) + ((lane >> 5) & 1);
                    const int bh_ = b * Hn + h;
                    unsigned short hi, lo;
                    bf_split(agv, hi, lo);
                    const size_t oidx = (size_t)bh_ * 16384
                        + (((a >> 4) * 2 + (c >> 5)) << 9) + (((c >> 3) & 3) << 7)
                        + ((a & 15) << 3) + (c & 7);
                    ag_hi[oidx] = hi; ag_lo[oidx] = lo;
                }
            }
        }
    }
}

// Output projection: flat grid 512, XCD-swizzled, fp32 flat out.
__global__ __launch_bounds__(256, 2)
void gemm_out(const unsigned short* __restrict__ Ahi_, const unsigned short* __restrict__ Alo_,
              const unsigned short* __restrict__ Bhi_, const unsigned short* __restrict__ Blo_,
              const float* __restrict__ bias, float* __restrict__ Cf)
{
    const int rem = blockIdx.x & 511;
    const int xcd = rem & 7, slot = rem >> 3;
    const int m0 = (xcd * 8 + (slot >> 3)) * MT;
    const int n0 = (slot & 7) * MT;

    GEMM_BODY(Ahi_, Alo_, Bhi_, Blo_)

    #pragma unroll
    for (int mi = 0; mi < 4; ++mi) {
        #pragma unroll
        for (int ni = 0; ni < 4; ++ni) {
            const int n = n0 + wc * 64 + ni * 16 + (lane & 15);
            const float bval = bias[n];
            #pragma unroll
            for (int j = 0; j < 4; ++j) {
                const int m = m0 + wr * 64 + mi * 16 + ((lane >> 4) << 2) + j;
                Cf[(size_t)m * Dsz + n] = acc[mi][ni][j] + bval;
            }
        }
    }
}

// ---------- flash stage-1: XCD-co-located flat grid (id&63 = bh) ----------
__global__ __launch_bounds__(256, 3)
void flash1(const unsigned short* __restrict__ ag_hi, const unsigned short* __restrict__ ag_lo,
            const unsigned short* __restrict__ kh_hi, const unsigned short* __restrict__ kh_lo,
            const unsigned short* __restrict__ vt_hi_g, const unsigned short* __restrict__ vt_lo_g,
            unsigned short* __restrict__ avt_hi, unsigned short* __restrict__ avt_lo)
{
    __shared__ unsigned short lds[24576];
    unsigned short* kth = lds;
    unsigned short* ktl = lds + 4096;
    unsigned short* vth = lds + 8192;
    unsigned short* vtl = lds + 12288;
    const int t = threadIdx.x;
    const int lane = t & 63, w = t >> 6;
    const int al15 = lane & 15, hi4 = lane >> 4;
    unsigned short* pwh = lds + 16384 + w * 2048;
    unsigned short* pwl = pwh + 1024;

    const int bh = blockIdx.x & 63;
    const int a0 = (blockIdx.x >> 6) * 64;

    bf16x8 bqh[2], bql[2];
    {
        const size_t abase = (size_t)bh * 16384 + (size_t)((a0 >> 4) + w) * 1024;
        #pragma unroll
        for (int ks = 0; ks < 2; ++ks) {
            bqh[ks] = gfrag(ag_hi + abase + ks * 512 + lane * 8);
            bql[ks] = gfrag(ag_lo + abase + ks * 512 + lane * 8);
        }
    }

    f32x4 O[4];
    #pragma unroll
    for (int i = 0; i < 4; ++i) O[i] = f32x4{0.f, 0.f, 0.f, 0.f};
    float m_run = -INFINITY, l_run = 0.f;

    for (int s0 = 0; s0 < Ssz; s0 += 64) {
        stage_tile<3, 2>(kh_hi + ((size_t)bh * Ssz + s0) * dh, dh, kth, t);
        stage_tile<3, 2>(kh_lo + ((size_t)bh * Ssz + s0) * dh, dh, ktl, t);
        stage_tile<3, 2>(vt_hi_g + (size_t)bh * dh * Ssz + s0, Ssz, vth, t);
        stage_tile<3, 2>(vt_lo_g + (size_t)bh * dh * Ssz + s0, Ssz, vtl, t);
        __syncthreads();

        f32x4 sc[4];
        #pragma unroll
        for (int si = 0; si < 4; ++si) sc[si] = f32x4{0.f, 0.f, 0.f, 0.f};
        #pragma unroll
        for (int si = 0; si < 4; ++si)
            #pragma unroll
            for (int ks = 0; ks < 2; ++ks) {
                bf16x8 ah = fragR<64>(kth, si * 16 + al15, ks, lane);
                bf16x8 al = fragR<64>(ktl, si * 16 + al15, ks, lane);
                sc[si] = __builtin_amdgcn_mfma_f32_16x16x32_bf16(ah, bqh[ks], sc[si], 0, 0, 0);
                sc[si] = __builtin_amdgcn_mfma_f32_16x16x32_bf16(ah, bql[ks], sc[si], 0, 0, 0);
                sc[si] = __builtin_amdgcn_mfma_f32_16x16x32_bf16(al, bqh[ks], sc[si], 0, 0, 0);
            }

        float tmax = -INFINITY;
        #pragma unroll
        for (int si = 0; si < 4; ++si)
            #pragma unroll
            for (int j = 0; j < 4; ++j) {
                sc[si][j] *= 0.125f;
                tmax = fmaxf(tmax, sc[si][j]);
            }
        tmax = fmaxf(tmax, __shfl_xor(tmax, 16));
        tmax = fmaxf(tmax, __shfl_xor(tmax, 32));
        float newm = fmaxf(m_run, tmax);
        float fac = __expf(m_run - newm);
        float tsum = 0.f;
        #pragma unroll
        for (int si = 0; si < 4; ++si)
            #pragma unroll
            for (int j = 0; j < 4; ++j) {
                float p = __expf(sc[si][j] - newm);
                sc[si][j] = p;
                tsum += p;
            }
        tsum += __shfl_xor(tsum, 16);
        tsum += __shfl_xor(tsum, 32);
        l_run = l_run * fac + tsum;
        m_run = newm;

        #pragma unroll
        for (int si = 0; si < 4; ++si) {
            ushort4 h4, l4;
            bf_split(sc[si][0], h4.x, l4.x);
            bf_split(sc[si][1], h4.y, l4.y);
            bf_split(sc[si][2], h4.z, l4.z);
            bf_split(sc[si][3], h4.w, l4.w);
            int baseS = si * 16 + (hi4 << 2);
            int addr = al15 * 64 + (baseS ^ ((al15 & 7) << 3));
            *reinterpret_cast<ushort4*>(pwh + addr) = h4;
            *reinterpret_cast<ushort4*>(pwl + addr) = l4;
        }

        float fj[4];
        #pragma unroll
        for (int j = 0; j < 4; ++j) fj[j] = __shfl(fac, (hi4 << 2) + j);
        #pragma unroll
        for (int di = 0; di < 4; ++di)
            #pragma unroll
            for (int j = 0; j < 4; ++j) O[di][j] *= fj[j];

        #pragma unroll
        for (int ks = 0; ks < 2; ++ks) {
            bf16x8 pah = fragR<64>(pwh, al15, ks, lane);
            bf16x8 pal = fragR<64>(pwl, al15, ks, lane);
            #pragma unroll
            for (int di = 0; di < 4; ++di) {
                bf16x8 vh = fragR<64>(vth, di * 16 + al15, ks, lane);
                bf16x8 vl = fragR<64>(vtl, di * 16 + al15, ks, lane);
                O[di] = __builtin_amdgcn_mfma_f32_16x16x32_bf16(pah, vh, O[di], 0, 0, 0);
                O[di] = __builtin_amdgcn_mfma_f32_16x16x32_bf16(pah, vl, O[di], 0, 0, 0);
                O[di] = __builtin_amdgcn_mfma_f32_16x16x32_bf16(pal, vh, O[di], 0, 0, 0);
            }
        }
        __syncthreads();
    }

    float lj[4];
    #pragma unroll
    for (int j = 0; j < 4; ++j) lj[j] = __shfl(l_run, (hi4 << 2) + j);
    #pragma unroll
    for (int di = 0; di < 4; ++di) {
        ushort4 h4, l4;
        #pragma unroll
        for (int j = 0; j < 4; ++j) {
            float val = O[di][j] / lj[j];
            unsigned short hi, lo;
            bf_split(val, hi, lo);
            ((unsigned short*)&h4)[j] = hi;
            ((unsigned short*)&l4)[j] = lo;
        }
        const size_t oidx = (size_t)bh * 16384
            + (size_t)(di * 8 + (a0 >> 5) + (w >> 1)) * 512
            + (size_t)((2 * w + (hi4 >> 1)) & 3) * 128
            + al15 * 8 + (hi4 & 1) * 4;
        *reinterpret_cast<ushort4*>(avt_hi + oidx) = h4;
        *reinterpret_cast<ushort4*>(avt_lo + oidx) = l4;
    }
}

// ---------- flash stage-2: XCD-co-located flat grid (id&63 = bh) ----------
__global__ __launch_bounds__(256, 2)
void flash2(const unsigned short* __restrict__ qh_hi, const unsigned short* __restrict__ qh_lo,
            const unsigned short* __restrict__ ag_hi, const unsigned short* __restrict__ ag_lo,
            const unsigned short* __restrict__ avt_hi, const unsigned short* __restrict__ avt_lo,
            float* __restrict__ q_attn,
            unsigned short* __restrict__ xo_hi, unsigned short* __restrict__ xo_lo)
{
    __shared__ float plds[4][4096];

    const int t = threadIdx.x, lane = t & 63, w = t >> 6;
    const int al15 = lane & 15, hi4 = lane >> 4;
    const int bh = blockIdx.x & 63;
    const int s0 = (blockIdx.x >> 6) * 64;
    float* P = plds[w];

    bf16x8 bqh[2], bql[2];
    {
        const size_t qbase = (size_t)bh * 131072 + (size_t)((s0 >> 4) + w) * 1024;
        #pragma unroll
        for (int ks = 0; ks < 2; ++ks) {
            bqh[ks] = gfrag(qh_hi + qbase + ks * 512 + lane * 8);
            bql[ks] = gfrag(qh_lo + qbase + ks * 512 + lane * 8);
        }
    }

    const unsigned short* agh = ag_hi + (size_t)bh * 16384;
    const unsigned short* agl = ag_lo + (size_t)bh * 16384;
    f32x4 acc[16];
    #pragma unroll
    for (int ai = 0; ai < 16; ++ai) acc[ai] = f32x4{0.f, 0.f, 0.f, 0.f};
    #pragma unroll
    for (int ai = 0; ai < 16; ++ai)
        #pragma unroll
        for (int ks = 0; ks < 2; ++ks) {
            bf16x8 ah = gfrag(agh + (ai * 2 + ks) * 512 + lane * 8);
            bf16x8 al = gfrag(agl + (ai * 2 + ks) * 512 + lane * 8);
            acc[ai] = __builtin_amdgcn_mfma_f32_16x16x32_bf16(ah, bqh[ks], acc[ai], 0, 0, 0);
            acc[ai] = __builtin_amdgcn_mfma_f32_16x16x32_bf16(ah, bql[ks], acc[ai], 0, 0, 0);
            acc[ai] = __builtin_amdgcn_mfma_f32_16x16x32_bf16(al, bqh[ks], acc[ai], 0, 0, 0);
        }

    float mx = -INFINITY;
    #pragma unroll
    for (int ai = 0; ai < 16; ++ai)
        #pragma unroll
        for (int j = 0; j < 4; ++j) {
            acc[ai][j] *= 0.125f;
            mx = fmaxf(mx, acc[ai][j]);
        }
    mx = fmaxf(mx, __shfl_xor(mx, 16));
    mx = fmaxf(mx, __shfl_xor(mx, 32));
    float sum = 0.f;
    #pragma unroll
    for (int ai = 0; ai < 16; ++ai)
        #pragma unroll
        for (int j = 0; j < 4; ++j) {
            float p = __expf(acc[ai][j] - mx);
            acc[ai][j] = p;
            sum += p;
        }
    sum += __shfl_xor(sum, 16);
    sum += __shfl_xor(sum, 32);
    const float inv = 1.0f / sum;

    #pragma unroll
    for (int ai = 0; ai < 16; ++ai) {
        float4 o;
        o.x = acc[ai][0] * inv; o.y = acc[ai][1] * inv;
        o.z = acc[ai][2] * inv; o.w = acc[ai][3] * inv;
        int pos4 = (ai * 4 + hi4) ^ (al15 & 7);
        *reinterpret_cast<float4*>(P + al15 * 256 + pos4 * 4) = o;
    }

    {
        float* qbase = q_attn + ((size_t)bh * Ssz + s0 + w * 16) * An;
        #pragma unroll
        for (int r = 0; r < 16; ++r) {
            float4 f = *reinterpret_cast<const float4*>(P + r * 256 + ((lane ^ (r & 7)) * 4));
            *reinterpret_cast<float4*>(qbase + r * An + lane * 4) = f;
        }
    }

    const unsigned short* avh_b = avt_hi + (size_t)bh * 16384;
    const unsigned short* avl_b = avt_lo + (size_t)bh * 16384;
    f32x4 O[4];
    #pragma unroll
    for (int i = 0; i < 4; ++i) O[i] = f32x4{0.f, 0.f, 0.f, 0.f};
    #pragma unroll
    for (int ks = 0; ks < 8; ++ks) {
        int p4 = ks * 8 + hi4 * 2;
        float4 fa = *reinterpret_cast<const float4*>(P + al15 * 256 + ((p4 ^ (al15 & 7)) * 4));
        float4 fb = *reinterpret_cast<const float4*>(P + al15 * 256 + (((p4 + 1) ^ (al15 & 7)) * 4));
        bf16x8 pah, pal;
        make8(fa, fb, pah, pal);
        #pragma unroll
        for (int di = 0; di < 4; ++di) {
            bf16x8 avh = gfrag(avh_b + (di * 8 + ks) * 512 + lane * 8);
            bf16x8 avl = gfrag(avl_b + (di * 8 + ks) * 512 + lane * 8);
            O[di] = __builtin_amdgcn_mfma_f32_16x16x32_bf16(pah, avh, O[di], 0, 0, 0);
            O[di] = __builtin_amdgcn_mfma_f32_16x16x32_bf16(pah, avl, O[di], 0, 0, 0);
            O[di] = __builtin_amdgcn_mfma_f32_16x16x32_bf16(pal, avh, O[di], 0, 0, 0);
        }
    }

    const int b = bh >> 4, h = bh & (Hn - 1);
    #pragma unroll
    for (int di = 0; di < 4; ++di)
        #pragma unroll
        for (int j = 0; j < 4; ++j) {
            float val = O[di][j];
            int sG = s0 + w * 16 + (hi4 << 2) + j;
            int dfull = h * dh + di * 16 + al15;
            size_t idx = ((size_t)b * Ssz + sG) * Dsz + dfull;
            unsigned short hi, lo;
            bf_split(val, hi, lo);
            xo_hi[idx] = hi; xo_lo[idx] = lo;
        }
}

extern "C" void kernel_launch(void* const* d_in, const int* in_sizes, int n_in,
                              void* d_out, int out_size, void* d_ws, size_t ws_size,
                              hipStream_t stream)
{
    const float* q  = (const float*)d_in[0];
    const float* k  = (const float*)d_in[1];
    const float* v  = (const float*)d_in[2];
    const float* Wq = (const float*)d_in[3];
    const float* bq = (const float*)d_in[4];
    const float* Wk = (const float*)d_in[5];
    const float* bk = (const float*)d_in[6];
    const float* Wv = (const float*)d_in[7];
    const float* bv = (const float*)d_in[8];
    const float* Wo = (const float*)d_in[9];
    const float* bo = (const float*)d_in[10];

    float* out    = (float*)d_out;
    float* q_attn = out + BSD;

    unsigned short* u = (unsigned short*)d_ws;
    unsigned short* xq_hi  = u;                 // q split; reused as out_h after flash2
    unsigned short* xq_lo  = xq_hi + BSD;
    unsigned short* xk_hi  = xq_lo + BSD;
    unsigned short* xk_lo  = xk_hi + BSD;
    unsigned short* xv_hi  = xk_lo + BSD;
    unsigned short* xv_lo  = xv_hi + BSD;
    unsigned short* qh_hi  = xv_lo + BSD;       // qh TILE layout
    unsigned short* qh_lo  = qh_hi + BSD;
    unsigned short* kh_hi  = qh_lo + BSD;       // [B,H,S,dh]
    unsigned short* kh_lo  = kh_hi + BSD;
    unsigned short* vt_hi  = kh_lo + BSD;       // [B,H,dh,S]
    unsigned short* vt_lo  = vt_hi + BSD;
    unsigned short* w_hi   = vt_lo + BSD;       // [4][D,D]
    unsigned short* w_lo   = w_hi + 4 * DD;
    unsigned short* ag_hi  = w_lo + 4 * DD;     // agents TILE
    unsigned short* ag_lo  = ag_hi + AGD;
    unsigned short* avt_hi = ag_lo + AGD;       // avt TILE
    unsigned short* avt_lo = avt_hi + AGD;

    // 1) all splits (2 launches)
    split_inputs<<<dim3(BSD / 1024, 3), 256, 0, stream>>>(
        q, k, v, xq_hi, xq_lo, xk_hi, xk_lo, xv_hi, xv_lo);
    split_weights<<<dim3(DD / 1024, 4), 256, 0, stream>>>(
        Wq, Wk, Wv, Wo, w_hi, w_lo);

    // 2) QKV projections (one launch, flat XCD-swizzled grid) + fused agent pooling
    gemm_qkv<<<1536, 256, 0, stream>>>(
        xq_hi, xq_lo, xk_hi, xk_lo, xv_hi, xv_lo, w_hi, w_lo,
        bq, bk, bv, qh_hi, qh_lo, kh_hi, kh_lo, vt_hi, vt_lo, ag_hi, ag_lo);

    // 3) stage 1 flash (XCD-co-located flat grid)
    flash1<<<256, 256, 0, stream>>>(
        ag_hi, ag_lo, kh_hi, kh_lo, vt_hi, vt_lo, avt_hi, avt_lo);

    // 4) stage 2 flash -> q_attn + out_h (into xq buffers)
    flash2<<<2048, 256, 0, stream>>>(
        qh_hi, qh_lo, ag_hi, ag_lo, avt_hi, avt_lo, q_attn, xq_hi, xq_lo);

    // 5) output projection (flat XCD-swizzled grid)
    gemm_out<<<512, 256, 0, stream>>>(
        xq_hi, xq_lo, w_hi + 3 * DD, w_lo + 3 * DD, bo, out);
}

// Round 17
// 352.468 us; speedup vs baseline: 1.3819x; 1.1431x over previous
//
#include <hip/hip_runtime.h>

// Problem constants
constexpr int Bsz = 4, Ssz = 2048, Dsz = 1024, Hn = 16, dh = 64, An = 256;
constexpr size_t BSD = (size_t)Bsz * Ssz * Dsz;    // 8,388,608
constexpr size_t DD  = (size_t)Dsz * Dsz;          // 1,048,576
constexpr size_t AGD = (size_t)Bsz * Hn * An * dh; // 1,048,576

typedef __attribute__((ext_vector_type(8))) short bf16x8;
typedef __attribute__((ext_vector_type(4))) float f32x4;

// ---------- helpers ----------
__device__ __forceinline__ unsigned short f2bf_rn(float f) {
    unsigned int u = __float_as_uint(f);
    return (unsigned short)((u + 0x7FFFu + ((u >> 16) & 1u)) >> 16);
}
__device__ __forceinline__ float bf2f(unsigned short h) {
    return __uint_as_float(((unsigned int)h) << 16);
}
__device__ __forceinline__ void bf_split(float f, unsigned short& hi, unsigned short& lo) {
    hi = f2bf_rn(f);
    lo = f2bf_rn(f - bf2f(hi));
}
__device__ __forceinline__ void gload16(const unsigned short* g, unsigned short* l) {
    __builtin_amdgcn_global_load_lds(
        (const __attribute__((address_space(1))) unsigned int*)g,
        (__attribute__((address_space(3))) unsigned int*)l, 16, 0, 0);
}
__device__ __forceinline__ bf16x8 gfrag(const unsigned short* g) {
    return *reinterpret_cast<const bf16x8*>(g);
}
__device__ __forceinline__ void make8(float4 a, float4 b, bf16x8& hi8, bf16x8& lo8) {
    float v[8] = {a.x, a.y, a.z, a.w, b.x, b.y, b.z, b.w};
    #pragma unroll
    for (int i = 0; i < 8; ++i) {
        unsigned short h, l;
        bf_split(v[i], h, l);
        hi8[i] = (short)h; lo8[i] = (short)l;
    }
}

// Stage a row-major tile into linear LDS with source-side chunk swizzle.
template<int LOGC, int NISS>
__device__ __forceinline__ void stage_tile(const unsigned short* __restrict__ g, long rowStride,
                                           unsigned short* lbase, int t) {
    const int wid = t >> 6;
    #pragma unroll
    for (int i = 0; i < NISS; ++i) {
        int slot = i * 256 + t;
        int r = slot >> LOGC;
        int c = slot & ((1 << LOGC) - 1);
        int cs = (c ^ (r & 7)) & ((1 << LOGC) - 1);
        gload16(g + (long)r * rowStride + cs * 8, lbase + (i * 256 + wid * 64) * 8);
    }
}
template<int ROWLEN>
__device__ __forceinline__ bf16x8 fragR(const unsigned short* buf, int row, int ks, int lane) {
    int c = ks * 4 + (lane >> 4);
    int cs = (c ^ (row & 7)) & (ROWLEN / 8 - 1);
    return *reinterpret_cast<const bf16x8*>(buf + row * ROWLEN + cs * 8);
}

// ---------- merged split kernel ----------
__device__ __forceinline__ void split4(const float* __restrict__ src,
                                       unsigned short* __restrict__ hi,
                                       unsigned short* __restrict__ lo, int i) {
    float4 v = reinterpret_cast<const float4*>(src)[i];
    ushort4 h, l;
    bf_split(v.x, h.x, l.x);
    bf_split(v.y, h.y, l.y);
    bf_split(v.z, h.z, l.z);
    bf_split(v.w, h.w, l.w);
    reinterpret_cast<ushort4*>(hi)[i] = h;
    reinterpret_cast<ushort4*>(lo)[i] = l;
}

// grid (BSD/1024 = 8192, 4): y=0..2 inputs; y=3 all four weights (first 4096 blocks)
__global__ __launch_bounds__(256)
void split_all(const float* __restrict__ q, const float* __restrict__ k,
               const float* __restrict__ v,
               const float* __restrict__ Wq, const float* __restrict__ Wk,
               const float* __restrict__ Wv, const float* __restrict__ Wo,
               unsigned short* __restrict__ xq_hi, unsigned short* __restrict__ xq_lo,
               unsigned short* __restrict__ xk_hi, unsigned short* __restrict__ xk_lo,
               unsigned short* __restrict__ xv_hi, unsigned short* __restrict__ xv_lo,
               unsigned short* __restrict__ w_hi, unsigned short* __restrict__ w_lo)
{
    const int job = blockIdx.y;
    if (job < 3) {
        const float* src = (job == 0) ? q : (job == 1) ? k : v;
        unsigned short* dh_ = (job == 0) ? xq_hi : (job == 1) ? xk_hi : xv_hi;
        unsigned short* dl_ = (job == 0) ? xq_lo : (job == 1) ? xk_lo : xv_lo;
        int i = blockIdx.x * 256 + threadIdx.x;
        split4(src, dh_, dl_, i);
    } else {
        if (blockIdx.x >= 4096) return;   // 4 weights x (DD/1024 = 1024) blocks
        const int wj = blockIdx.x >> 10;
        const float* src = (wj == 0) ? Wq : (wj == 1) ? Wk : (wj == 2) ? Wv : Wo;
        int i = (blockIdx.x & 1023) * 256 + threadIdx.x;
        split4(src, w_hi + (size_t)wj * DD, w_lo + (size_t)wj * DD, i);
    }
}

// ---------- split-bf16 MFMA GEMM core ----------
#define MT 128
#define BKm 32

__device__ __forceinline__ bf16x8 lds_frag(const unsigned short* buf, int baseRow, int lane) {
    int row = baseRow + (lane & 15);
    int c = lane >> 4;
    int idx = row * 32 + ((c ^ ((row >> 1) & 3)) << 3);
    return *reinterpret_cast<const bf16x8*>(buf + idx);
}

// GEMM body: expects `const int m0, n0` already defined in scope.
#define GEMM_BODY(Ahi, Alo, Bhi, Blo)                                                   \
    __shared__ unsigned short lds[4 * 4096];                                            \
    const int t = threadIdx.x;                                                          \
    const int lane = t & 63, wid = t >> 6;                                              \
    const int wr = wid >> 1, wc = wid & 1;                                              \
    const int srow0 = t >> 2;                                                           \
    const int x4 = t & 3;                                                               \
    const int ldsBase0 = (wid * 64) * 8;                                                \
    const int ldsBase1 = (256 + wid * 64) * 8;                                          \
    f32x4 acc[4][4];                                                                    \
    _Pragma("unroll")                                                                   \
    for (int i = 0; i < 4; ++i)                                                         \
        _Pragma("unroll")                                                               \
        for (int j = 0; j < 4; ++j)                                                     \
            acc[i][j] = f32x4{0.f, 0.f, 0.f, 0.f};                                      \
    const unsigned short* gA[2] = {Ahi, Alo};                                           \
    const unsigned short* gB[2] = {Bhi, Blo};                                           \
    for (int k0 = 0; k0 < Dsz; k0 += BKm) {                                             \
        _Pragma("unroll")                                                               \
        for (int hb = 0; hb < 2; ++hb) {                                                \
            {                                                                           \
                const unsigned short* G = gA[hb];                                       \
                int r0 = srow0, r1 = srow0 + 64;                                        \
                int c0 = x4 ^ ((r0 >> 1) & 3);                                          \
                int c1 = x4 ^ ((r1 >> 1) & 3);                                          \
                gload16(G + (size_t)(m0 + r0) * Dsz + k0 + c0 * 8, lds + hb * 4096 + ldsBase0); \
                gload16(G + (size_t)(m0 + r1) * Dsz + k0 + c1 * 8, lds + hb * 4096 + ldsBase1); \
            }                                                                           \
            {                                                                           \
                const unsigned short* G = gB[hb];                                       \
                int r0 = srow0, r1 = srow0 + 64;                                        \
                int c0 = x4 ^ ((r0 >> 1) & 3);                                          \
                int c1 = x4 ^ ((r1 >> 1) & 3);                                          \
                gload16(G + (size_t)(n0 + r0) * Dsz + k0 + c0 * 8, lds + (2 + hb) * 4096 + ldsBase0); \
                gload16(G + (size_t)(n0 + r1) * Dsz + k0 + c1 * 8, lds + (2 + hb) * 4096 + ldsBase1); \
            }                                                                           \
        }                                                                               \
        __syncthreads();                                                                \
        bf16x8 ah[4], al[4], bh[4], bl[4];                                              \
        _Pragma("unroll")                                                               \
        for (int mi = 0; mi < 4; ++mi) {                                                \
            ah[mi] = lds_frag(lds + 0 * 4096, wr * 64 + mi * 16, lane);                 \
            al[mi] = lds_frag(lds + 1 * 4096, wr * 64 + mi * 16, lane);                 \
        }                                                                               \
        _Pragma("unroll")                                                               \
        for (int ni = 0; ni < 4; ++ni) {                                                \
            bh[ni] = lds_frag(lds + 2 * 4096, wc * 64 + ni * 16, lane);                 \
            bl[ni] = lds_frag(lds + 3 * 4096, wc * 64 + ni * 16, lane);                 \
        }                                                                               \
        _Pragma("unroll")                                                               \
        for (int mi = 0; mi < 4; ++mi)                                                  \
            _Pragma("unroll")                                                           \
            for (int ni = 0; ni < 4; ++ni) {                                            \
                acc[mi][ni] = __builtin_amdgcn_mfma_f32_16x16x32_bf16(ah[mi], bh[ni], acc[mi][ni], 0, 0, 0); \
                acc[mi][ni] = __builtin_amdgcn_mfma_f32_16x16x32_bf16(ah[mi], bl[ni], acc[mi][ni], 0, 0, 0); \
                acc[mi][ni] = __builtin_amdgcn_mfma_f32_16x16x32_bf16(al[mi], bh[ni], acc[mi][ni], 0, 0, 0); \
            }                                                                           \
        __syncthreads();                                                                \
    }

// QKV merged projection: flat grid 1536, XCD-swizzled.
// z = id>>9. Within z: xcd = rem&7 owns m-panels [xcd*8, xcd*8+8), n fastest.
// z==0 additionally pools agents from exact fp32 values; z==2 uses packed ushort4 stores.
__global__ __launch_bounds__(256, 2)
void gemm_qkv(const unsigned short* __restrict__ xq_hi, const unsigned short* __restrict__ xq_lo,
              const unsigned short* __restrict__ xk_hi, const unsigned short* __restrict__ xk_lo,
              const unsigned short* __restrict__ xv_hi, const unsigned short* __restrict__ xv_lo,
              const unsigned short* __restrict__ w_hi, const unsigned short* __restrict__ w_lo,
              const float* __restrict__ bq, const float* __restrict__ bk, const float* __restrict__ bv,
              unsigned short* __restrict__ qh_hi, unsigned short* __restrict__ qh_lo,
              unsigned short* __restrict__ kh_hi, unsigned short* __restrict__ kh_lo,
              unsigned short* __restrict__ vt_hi, unsigned short* __restrict__ vt_lo,
              unsigned short* __restrict__ ag_hi, unsigned short* __restrict__ ag_lo)
{
    const int id = blockIdx.x;
    const int z = id >> 9;
    const int rem = id & 511;
    const int xcd = rem & 7, slot = rem >> 3;
    const int m0 = (xcd * 8 + (slot >> 3)) * MT;
    const int n0 = (slot & 7) * MT;

    const unsigned short* Ahi = (z == 0) ? xq_hi : (z == 1) ? xk_hi : xv_hi;
    const unsigned short* Alo = (z == 0) ? xq_lo : (z == 1) ? xk_lo : xv_lo;
    const unsigned short* Bhi = w_hi + (size_t)z * DD;
    const unsigned short* Blo = w_lo + (size_t)z * DD;
    const float* bias = (z == 0) ? bq : (z == 1) ? bk : bv;
    unsigned short* Chi = (z == 0) ? qh_hi : (z == 1) ? kh_hi : vt_hi;
    unsigned short* Clo = (z == 0) ? qh_lo : (z == 1) ? kh_lo : vt_lo;

    GEMM_BODY(Ahi, Alo, Bhi, Blo)

    #pragma unroll
    for (int mi = 0; mi < 4; ++mi) {
        #pragma unroll
        for (int ni = 0; ni < 4; ++ni) {
            const int n = n0 + wc * 64 + ni * 16 + (lane & 15);
            const float bval = bias[n];
            if (z == 2) {
                // vt layout is s-contiguous: pack 4 consecutive s into ushort4
                ushort4 h4, l4;
                #pragma unroll
                for (int j = 0; j < 4; ++j) {
                    unsigned short hi, lo;
                    bf_split(acc[mi][ni][j] + bval, hi, lo);
                    ((unsigned short*)&h4)[j] = hi;
                    ((unsigned short*)&l4)[j] = lo;
                }
                const int m = m0 + wr * 64 + mi * 16 + ((lane >> 4) << 2);
                const int b = m >> 11, s = m & (Ssz - 1);
                const int h = n >> 6, c = n & (dh - 1);
                const size_t idx = (((size_t)(b * Hn + h)) * dh + c) * Ssz + s;
                *reinterpret_cast<ushort4*>(Chi + idx) = h4;
                *reinterpret_cast<ushort4*>(Clo + idx) = l4;
            } else {
                float psum = 0.f;
                #pragma unroll
                for (int j = 0; j < 4; ++j) {
                    const int m = m0 + wr * 64 + mi * 16 + ((lane >> 4) << 2) + j;
                    float val = acc[mi][ni][j] + bval;
                    psum += val;
                    const int b = m >> 11, s = m & (Ssz - 1);
                    const int h = n >> 6, c = n & (dh - 1);
                    size_t idx;
                    if (z == 0)
                        idx = (size_t)(b * Hn + h) * 131072
                            + (((s >> 4) * 2 + (c >> 5)) << 9)
                            + (((c >> 3) & 3) << 7) + ((s & 15) << 3) + (c & 7);
                    else
                        idx = (((size_t)(b * Hn + h)) * Ssz + s) * dh + c;
                    unsigned short hi, lo;
                    bf_split(val, hi, lo);
                    Chi[idx] = hi; Clo[idx] = lo;
                }
                if (z == 0) {
                    // fused agent pooling: 16 rows of this fragment = 2 agents (8 rows each)
                    psum += __shfl_xor(psum, 16);
                    if (((lane >> 4) & 1) == 0) {
                        const float agv = psum * 0.125f;
                        const int mrow = m0 + wr * 64 + mi * 16;
                        const int b = mrow >> 11, sRow = mrow & (Ssz - 1);
                        const int h = n >> 6, c = n & (dh - 1);
                        const int a = (sRow >> 3) + ((lane >> 5) & 1);
                        const int bh_ = b * Hn + h;
                        unsigned short hi, lo;
                        bf_split(agv, hi, lo);
                        const size_t oidx = (size_t)bh_ * 16384
                            + (((a >> 4) * 2 + (c >> 5)) << 9) + (((c >> 3) & 3) << 7)
                            + ((a & 15) << 3) + (c & 7);
                        ag_hi[oidx] = hi; ag_lo[oidx] = lo;
                    }
                }
            }
        }
    }
}

// Output projection: flat grid 512, XCD-swizzled, fp32 flat out.
__global__ __launch_bounds__(256, 2)
void gemm_out(const unsigned short* __restrict__ Ahi_, const unsigned short* __restrict__ Alo_,
              const unsigned short* __restrict__ Bhi_, const unsigned short* __restrict__ Blo_,
              const float* __restrict__ bias, float* __restrict__ Cf)
{
    const int rem = blockIdx.x & 511;
    const int xcd = rem & 7, slot = rem >> 3;
    const int m0 = (xcd * 8 + (slot >> 3)) * MT;
    const int n0 = (slot & 7) * MT;

    GEMM_BODY(Ahi_, Alo_, Bhi_, Blo_)

    #pragma unroll
    for (int mi = 0; mi < 4; ++mi) {
        #pragma unroll
        for (int ni = 0; ni < 4; ++ni) {
            const int n = n0 + wc * 64 + ni * 16 + (lane & 15);
            const float bval = bias[n];
            #pragma unroll
            for (int j = 0; j < 4; ++j) {
                const int m = m0 + wr * 64 + mi * 16 + ((lane >> 4) << 2) + j;
                Cf[(size_t)m * Dsz + n] = acc[mi][ni][j] + bval;
            }
        }
    }
}

// ---------- flash stage-1: XCD-co-located flat grid (id&63 = bh) ----------
__global__ __launch_bounds__(256, 3)
void flash1(const unsigned short* __restrict__ ag_hi, const unsigned short* __restrict__ ag_lo,
            const unsigned short* __restrict__ kh_hi, const unsigned short* __restrict__ kh_lo,
            const unsigned short* __restrict__ vt_hi_g, const unsigned short* __restrict__ vt_lo_g,
            unsigned short* __restrict__ avt_hi, unsigned short* __restrict__ avt_lo)
{
    __shared__ unsigned short lds[24576];
    unsigned short* kth = lds;
    unsigned short* ktl = lds + 4096;
    unsigned short* vth = lds + 8192;
    unsigned short* vtl = lds + 12288;
    const int t = threadIdx.x;
    const int lane = t & 63, w = t >> 6;
    const int al15 = lane & 15, hi4 = lane >> 4;
    unsigned short* pwh = lds + 16384 + w * 2048;
    unsigned short* pwl = pwh + 1024;

    const int bh = blockIdx.x & 63;
    const int a0 = (blockIdx.x >> 6) * 64;

    bf16x8 bqh[2], bql[2];
    {
        const size_t abase = (size_t)bh * 16384 + (size_t)((a0 >> 4) + w) * 1024;
        #pragma unroll
        for (int ks = 0; ks < 2; ++ks) {
            bqh[ks] = gfrag(ag_hi + abase + ks * 512 + lane * 8);
            bql[ks] = gfrag(ag_lo + abase + ks * 512 + lane * 8);
        }
    }

    f32x4 O[4];
    #pragma unroll
    for (int i = 0; i < 4; ++i) O[i] = f32x4{0.f, 0.f, 0.f, 0.f};
    float m_run = -INFINITY, l_run = 0.f;

    for (int s0 = 0; s0 < Ssz; s0 += 64) {
        stage_tile<3, 2>(kh_hi + ((size_t)bh * Ssz + s0) * dh, dh, kth, t);
        stage_tile<3, 2>(kh_lo + ((size_t)bh * Ssz + s0) * dh, dh, ktl, t);
        stage_tile<3, 2>(vt_hi_g + (size_t)bh * dh * Ssz + s0, Ssz, vth, t);
        stage_tile<3, 2>(vt_lo_g + (size_t)bh * dh * Ssz + s0, Ssz, vtl, t);
        __syncthreads();

        f32x4 sc[4];
        #pragma unroll
        for (int si = 0; si < 4; ++si) sc[si] = f32x4{0.f, 0.f, 0.f, 0.f};
        #pragma unroll
        for (int si = 0; si < 4; ++si)
            #pragma unroll
            for (int ks = 0; ks < 2; ++ks) {
                bf16x8 ah = fragR<64>(kth, si * 16 + al15, ks, lane);
                bf16x8 al = fragR<64>(ktl, si * 16 + al15, ks, lane);
                sc[si] = __builtin_amdgcn_mfma_f32_16x16x32_bf16(ah, bqh[ks], sc[si], 0, 0, 0);
                sc[si] = __builtin_amdgcn_mfma_f32_16x16x32_bf16(ah, bql[ks], sc[si], 0, 0, 0);
                sc[si] = __builtin_amdgcn_mfma_f32_16x16x32_bf16(al, bqh[ks], sc[si], 0, 0, 0);
            }

        float tmax = -INFINITY;
        #pragma unroll
        for (int si = 0; si < 4; ++si)
            #pragma unroll
            for (int j = 0; j < 4; ++j) {
                sc[si][j] *= 0.125f;
                tmax = fmaxf(tmax, sc[si][j]);
            }
        tmax = fmaxf(tmax, __shfl_xor(tmax, 16));
        tmax = fmaxf(tmax, __shfl_xor(tmax, 32));
        float newm = fmaxf(m_run, tmax);
        float fac = __expf(m_run - newm);
        float tsum = 0.f;
        #pragma unroll
        for (int si = 0; si < 4; ++si)
            #pragma unroll
            for (int j = 0; j < 4; ++j) {
                float p = __expf(sc[si][j] - newm);
                sc[si][j] = p;
                tsum += p;
            }
        tsum += __shfl_xor(tsum, 16);
        tsum += __shfl_xor(tsum, 32);
        l_run = l_run * fac + tsum;
        m_run = newm;

        #pragma unroll
        for (int si = 0; si < 4; ++si) {
            ushort4 h4, l4;
            bf_split(sc[si][0], h4.x, l4.x);
            bf_split(sc[si][1], h4.y, l4.y);
            bf_split(sc[si][2], h4.z, l4.z);
            bf_split(sc[si][3], h4.w, l4.w);
            int baseS = si * 16 + (hi4 << 2);
            int addr = al15 * 64 + (baseS ^ ((al15 & 7) << 3));
            *reinterpret_cast<ushort4*>(pwh + addr) = h4;
            *reinterpret_cast<ushort4*>(pwl + addr) = l4;
        }

        float fj[4];
        #pragma unroll
        for (int j = 0; j < 4; ++j) fj[j] = __shfl(fac, (hi4 << 2) + j);
        #pragma unroll
        for (int di = 0; di < 4; ++di)
            #pragma unroll
            for (int j = 0; j < 4; ++j) O[di][j] *= fj[j];

        #pragma unroll
        for (int ks = 0; ks < 2; ++ks) {
            bf16x8 pah = fragR<64>(pwh, al15, ks, lane);
            bf16x8 pal = fragR<64>(pwl, al15, ks, lane);
            #pragma unroll
            for (int di = 0; di < 4; ++di) {
                bf16x8 vh = fragR<64>(vth, di * 16 + al15, ks, lane);
                bf16x8 vl = fragR<64>(vtl, di * 16 + al15, ks, lane);
                O[di] = __builtin_amdgcn_mfma_f32_16x16x32_bf16(pah, vh, O[di], 0, 0, 0);
                O[di] = __builtin_amdgcn_mfma_f32_16x16x32_bf16(pah, vl, O[di], 0, 0, 0);
                O[di] = __builtin_amdgcn_mfma_f32_16x16x32_bf16(pal, vh, O[di], 0, 0, 0);
            }
        }
        __syncthreads();
    }

    float lj[4];
    #pragma unroll
    for (int j = 0; j < 4; ++j) lj[j] = __shfl(l_run, (hi4 << 2) + j);
    #pragma unroll
    for (int di = 0; di < 4; ++di) {
        ushort4 h4, l4;
        #pragma unroll
        for (int j = 0; j < 4; ++j) {
            float val = O[di][j] / lj[j];
            unsigned short hi, lo;
            bf_split(val, hi, lo);
            ((unsigned short*)&h4)[j] = hi;
            ((unsigned short*)&l4)[j] = lo;
        }
        const size_t oidx = (size_t)bh * 16384
            + (size_t)(di * 8 + (a0 >> 5) + (w >> 1)) * 512
            + (size_t)((2 * w + (hi4 >> 1)) & 3) * 128
            + al15 * 8 + (hi4 & 1) * 4;
        *reinterpret_cast<ushort4*>(avt_hi + oidx) = h4;
        *reinterpret_cast<ushort4*>(avt_lo + oidx) = l4;
    }
}

// ---------- flash stage-2: XCD-co-located flat grid (id&63 = bh) ----------
__global__ __launch_bounds__(256, 2)
void flash2(const unsigned short* __restrict__ qh_hi, const unsigned short* __restrict__ qh_lo,
            const unsigned short* __restrict__ ag_hi, const unsigned short* __restrict__ ag_lo,
            const unsigned short* __restrict__ avt_hi, const unsigned short* __restrict__ avt_lo,
            float* __restrict__ q_attn,
            unsigned short* __restrict__ xo_hi, unsigned short* __restrict__ xo_lo)
{
    __shared__ float plds[4][4096];

    const int t = threadIdx.x, lane = t & 63, w = t >> 6;
    const int al15 = lane & 15, hi4 = lane >> 4;
    const int bh = blockIdx.x & 63;
    const int s0 = (blockIdx.x >> 6) * 64;
    float* P = plds[w];

    bf16x8 bqh[2], bql[2];
    {
        const size_t qbase = (size_t)bh * 131072 + (size_t)((s0 >> 4) + w) * 1024;
        #pragma unroll
        for (int ks = 0; ks < 2; ++ks) {
            bqh[ks] = gfrag(qh_hi + qbase + ks * 512 + lane * 8);
            bql[ks] = gfrag(qh_lo + qbase + ks * 512 + lane * 8);
        }
    }

    const unsigned short* agh = ag_hi + (size_t)bh * 16384;
    const unsigned short* agl = ag_lo + (size_t)bh * 16384;
    f32x4 acc[16];
    #pragma unroll
    for (int ai = 0; ai < 16; ++ai) acc[ai] = f32x4{0.f, 0.f, 0.f, 0.f};
    #pragma unroll
    for (int ai = 0; ai < 16; ++ai)
        #pragma unroll
        for (int ks = 0; ks < 2; ++ks) {
            bf16x8 ah = gfrag(agh + (ai * 2 + ks) * 512 + lane * 8);
            bf16x8 al = gfrag(agl + (ai * 2 + ks) * 512 + lane * 8);
            acc[ai] = __builtin_amdgcn_mfma_f32_16x16x32_bf16(ah, bqh[ks], acc[ai], 0, 0, 0);
            acc[ai] = __builtin_amdgcn_mfma_f32_16x16x32_bf16(ah, bql[ks], acc[ai], 0, 0, 0);
            acc[ai] = __builtin_amdgcn_mfma_f32_16x16x32_bf16(al, bqh[ks], acc[ai], 0, 0, 0);
        }

    float mx = -INFINITY;
    #pragma unroll
    for (int ai = 0; ai < 16; ++ai)
        #pragma unroll
        for (int j = 0; j < 4; ++j) {
            acc[ai][j] *= 0.125f;
            mx = fmaxf(mx, acc[ai][j]);
        }
    mx = fmaxf(mx, __shfl_xor(mx, 16));
    mx = fmaxf(mx, __shfl_xor(mx, 32));
    float sum = 0.f;
    #pragma unroll
    for (int ai = 0; ai < 16; ++ai)
        #pragma unroll
        for (int j = 0; j < 4; ++j) {
            float p = __expf(acc[ai][j] - mx);
            acc[ai][j] = p;
            sum += p;
        }
    sum += __shfl_xor(sum, 16);
    sum += __shfl_xor(sum, 32);
    const float inv = 1.0f / sum;

    #pragma unroll
    for (int ai = 0; ai < 16; ++ai) {
        float4 o;
        o.x = acc[ai][0] * inv; o.y = acc[ai][1] * inv;
        o.z = acc[ai][2] * inv; o.w = acc[ai][3] * inv;
        int pos4 = (ai * 4 + hi4) ^ (al15 & 7);
        *reinterpret_cast<float4*>(P + al15 * 256 + pos4 * 4) = o;
    }

    {
        float* qbase = q_attn + ((size_t)bh * Ssz + s0 + w * 16) * An;
        #pragma unroll
        for (int r = 0; r < 16; ++r) {
            f32x4 f = *reinterpret_cast<const f32x4*>(P + r * 256 + ((lane ^ (r & 7)) * 4));
            __builtin_nontemporal_store(f, reinterpret_cast<f32x4*>(qbase + r * An + lane * 4));
        }
    }

    const unsigned short* avh_b = avt_hi + (size_t)bh * 16384;
    const unsigned short* avl_b = avt_lo + (size_t)bh * 16384;
    f32x4 O[4];
    #pragma unroll
    for (int i = 0; i < 4; ++i) O[i] = f32x4{0.f, 0.f, 0.f, 0.f};
    #pragma unroll
    for (int ks = 0; ks < 8; ++ks) {
        int p4 = ks * 8 + hi4 * 2;
        float4 fa = *reinterpret_cast<const float4*>(P + al15 * 256 + ((p4 ^ (al15 & 7)) * 4));
        float4 fb = *reinterpret_cast<const float4*>(P + al15 * 256 + (((p4 + 1) ^ (al15 & 7)) * 4));
        bf16x8 pah, pal;
        make8(fa, fb, pah, pal);
        #pragma unroll
        for (int di = 0; di < 4; ++di) {
            bf16x8 avh = gfrag(avh_b + (di * 8 + ks) * 512 + lane * 8);
            bf16x8 avl = gfrag(avl_b + (di * 8 + ks) * 512 + lane * 8);
            O[di] = __builtin_amdgcn_mfma_f32_16x16x32_bf16(pah, avh, O[di], 0, 0, 0);
            O[di] = __builtin_amdgcn_mfma_f32_16x16x32_bf16(pah, avl, O[di], 0, 0, 0);
            O[di] = __builtin_amdgcn_mfma_f32_16x16x32_bf16(pal, avh, O[di], 0, 0, 0);
        }
    }

    const int b = bh >> 4, h = bh & (Hn - 1);
    #pragma unroll
    for (int di = 0; di < 4; ++di)
        #pragma unroll
        for (int j = 0; j < 4; ++j) {
            float val = O[di][j];
            int sG = s0 + w * 16 + (hi4 << 2) + j;
            int dfull = h * dh + di * 16 + al15;
            size_t idx = ((size_t)b * Ssz + sG) * Dsz + dfull;
            unsigned short hi, lo;
            bf_split(val, hi, lo);
            xo_hi[idx] = hi; xo_lo[idx] = lo;
        }
}

extern "C" void kernel_launch(void* const* d_in, const int* in_sizes, int n_in,
                              void* d_out, int out_size, void* d_ws, size_t ws_size,
                              hipStream_t stream)
{
    const float* q  = (const float*)d_in[0];
    const float* k  = (const float*)d_in[1];
    const float* v  = (const float*)d_in[2];
    const float* Wq = (const float*)d_in[3];
    const float* bq = (const float*)d_in[4];
    const float* Wk = (const float*)d_in[5];
    const float* bk = (const float*)d_in[6];
    const float* Wv = (const float*)d_in[7];
    const float* bv = (const float*)d_in[8];
    const float* Wo = (const float*)d_in[9];
    const float* bo = (const float*)d_in[10];

    float* out    = (float*)d_out;
    float* q_attn = out + BSD;

    unsigned short* u = (unsigned short*)d_ws;
    unsigned short* xq_hi  = u;                 // q split; reused as out_h after flash2
    unsigned short* xq_lo  = xq_hi + BSD;
    unsigned short* xk_hi  = xq_lo + BSD;
    unsigned short* xk_lo  = xk_hi + BSD;
    unsigned short* xv_hi  = xk_lo + BSD;
    unsigned short* xv_lo  = xv_hi + BSD;
    unsigned short* qh_hi  = xv_lo + BSD;       // qh TILE layout
    unsigned short* qh_lo  = qh_hi + BSD;
    unsigned short* kh_hi  = qh_lo + BSD;       // [B,H,S,dh]
    unsigned short* kh_lo  = kh_hi + BSD;
    unsigned short* vt_hi  = kh_lo + BSD;       // [B,H,dh,S]
    unsigned short* vt_lo  = vt_hi + BSD;
    unsigned short* w_hi   = vt_lo + BSD;       // [4][D,D]
    unsigned short* w_lo   = w_hi + 4 * DD;
    unsigned short* ag_hi  = w_lo + 4 * DD;     // agents TILE
    unsigned short* ag_lo  = ag_hi + AGD;
    unsigned short* avt_hi = ag_lo + AGD;       // avt TILE
    unsigned short* avt_lo = avt_hi + AGD;

    // 1) all splits (one launch)
    split_all<<<dim3(BSD / 1024, 4), 256, 0, stream>>>(
        q, k, v, Wq, Wk, Wv, Wo,
        xq_hi, xq_lo, xk_hi, xk_lo, xv_hi, xv_lo, w_hi, w_lo);

    // 2) QKV projections (one launch, flat XCD-swizzled grid) + fused agent pooling
    gemm_qkv<<<1536, 256, 0, stream>>>(
        xq_hi, xq_lo, xk_hi, xk_lo, xv_hi, xv_lo, w_hi, w_lo,
        bq, bk, bv, qh_hi, qh_lo, kh_hi, kh_lo, vt_hi, vt_lo, ag_hi, ag_lo);

    // 3) stage 1 flash (XCD-co-located flat grid)
    flash1<<<256, 256, 0, stream>>>(
        ag_hi, ag_lo, kh_hi, kh_lo, vt_hi, vt_lo, avt_hi, avt_lo);

    // 4) stage 2 flash -> q_attn + out_h (into xq buffers)
    flash2<<<2048, 256, 0, stream>>>(
        qh_hi, qh_lo, ag_hi, ag_lo, avt_hi, avt_lo, q_attn, xq_hi, xq_lo);

    // 5) output projection (flat XCD-swizzled grid)
    gemm_out<<<512, 256, 0, stream>>>(
        xq_hi, xq_lo, w_hi + 3 * DD, w_lo + 3 * DD, bo, out);
}